// Round 9
// baseline (1449.028 us; speedup 1.0000x reference)
//
#include <hip/hip_runtime.h>
#include <hip/hip_bf16.h>
#include <math.h>

#define VSZ 2048
#define EDIM 256
#define HDIM 256
#define G4 1024   // 4*H
#define TMAX 16
#define IB 16     // instructions per workgroup in token-LSTM (MFMA M=16)

typedef _Float16 f16x2 __attribute__((ext_vector_type(2)));
typedef _Float16 f16x4 __attribute__((ext_vector_type(4)));
typedef _Float16 f16x8 __attribute__((ext_vector_type(8)));
typedef float f32x4 __attribute__((ext_vector_type(4)));

#define HA_STRIDE 264   // fp16 elems per hA row (256 + 8 pad)
#define GH_STRIDE 132   // fp16 elems per half-gate staging row (128 + 4 pad)

// ---- fast activations: v_exp_f32 / v_rcp_f32 based (verified rounds 2-8) ----
__device__ __forceinline__ float fexp2(float x) {
#if defined(__has_builtin) && __has_builtin(__builtin_amdgcn_exp2f)
  return __builtin_amdgcn_exp2f(x);
#else
  return exp2f(x);
#endif
}
__device__ __forceinline__ float frcp(float x) {
#if defined(__has_builtin) && __has_builtin(__builtin_amdgcn_rcpf)
  return __builtin_amdgcn_rcpf(x);
#else
  return 1.0f / x;
#endif
}
__device__ __forceinline__ float sigm(float x) {
  return frcp(1.0f + fexp2(x * -1.44269504f));
}
__device__ __forceinline__ float tanh_fast(float x) {
  float t = fexp2(fminf(x, 15.0f) * 2.88539008f);
  return (t - 1.0f) * frcp(t + 1.0f);
}

__device__ __forceinline__ float fdot2(f16x2 a, f16x2 b, float c) {
#if defined(__has_builtin) && __has_builtin(__builtin_amdgcn_fdot2)
  return __builtin_amdgcn_fdot2(a, b, c, false);
#else
  return c + (float)a.x * (float)b.x + (float)a.y * (float)b.y;
#endif
}

__device__ __forceinline__ float dot8h(uint4 w, float4 hv, float acc) {
  f16x2 h0 = __builtin_bit_cast(f16x2, hv.x);
  f16x2 h1 = __builtin_bit_cast(f16x2, hv.y);
  f16x2 h2 = __builtin_bit_cast(f16x2, hv.z);
  f16x2 h3 = __builtin_bit_cast(f16x2, hv.w);
  f16x2 w0 = __builtin_bit_cast(f16x2, w.x);
  f16x2 w1 = __builtin_bit_cast(f16x2, w.y);
  f16x2 w2 = __builtin_bit_cast(f16x2, w.z);
  f16x2 w3 = __builtin_bit_cast(f16x2, w.w);
  return fdot2(h3, w3, fdot2(h2, w2, fdot2(h1, w1, fdot2(h0, w0, acc))));
}

// ---- dtype probes ----
__device__ __forceinline__ bool is_f32(const void* w) {
  const unsigned short* p = (const unsigned short*)w;
  int pl = 0;
#pragma unroll
  for (int i = 0; i < 64; ++i) {
    unsigned e = (p[2 * i] >> 7) & 0xFF;
    pl += (e >= 113 && e <= 122) ? 1 : 0;
  }
  return pl < 48;
}

// ---- typed loads ----
template <bool F32>
__device__ __forceinline__ float ldf(const void* p, long j) {
  if (F32) return ((const float*)p)[j];
  return __uint_as_float(((unsigned)((const unsigned short*)p)[j]) << 16);
}
__device__ __forceinline__ float ldf_rt(const void* p, long j, bool f32) {
  if (f32) return ((const float*)p)[j];
  return __uint_as_float(((unsigned)((const unsigned short*)p)[j]) << 16);
}
template <bool I64>
__device__ __forceinline__ int ldi(const int* p, int j) {
  return I64 ? p[2 * j] : p[j];
}
__device__ __forceinline__ int ldi_rt(const int* p, int j, bool i64) {
  return i64 ? p[2 * j] : p[j];
}

// ===== fp32 transpose: dst[k*1024 + r] = src[r*256 + k] =====
__global__ __launch_bounds__(256) void k_transp(const void* src, float* __restrict__ dst,
                                                const void* fprobe) {
  __shared__ float tile[32][33];
  __shared__ int sf;
  if (threadIdx.x == 0) sf = is_f32(fprobe) ? 1 : 0;
  __syncthreads();
  const bool f32 = (sf != 0);
  const int tx = threadIdx.x & 31, ty = threadIdx.x >> 5;
  const int r0 = blockIdx.x * 32, c0 = blockIdx.y * 32;
#pragma unroll
  for (int q = 0; q < 4; ++q) {
    int rr = ty + q * 8;
    tile[rr][tx] = ldf_rt(src, (long)(r0 + rr) * 256 + (c0 + tx), f32);
  }
  __syncthreads();
#pragma unroll
  for (int q = 0; q < 4; ++q) {
    int cc = ty + q * 8;
    dst[(size_t)(c0 + cc) * 1024 + (r0 + tx)] = tile[tx][cc];
  }
}

// ===== fp16 weight packing (row-gang layout for k_ins_rec) =====
__global__ __launch_bounds__(256) void k_pack(const void* src, uint4* __restrict__ dst,
                                              const void* fprobe) {
  __shared__ int sf;
  if (threadIdx.x == 0) sf = is_f32(fprobe) ? 1 : 0;
  __syncthreads();
  const bool f32 = (sf != 0);
  const int idx = blockIdx.x * 256 + threadIdx.x;  // grid 128
  const int rr = idx & 255, j = (idx >> 8) & 3, c = idx >> 10;
  const long base = (long)(j * 256 + rr) * 256 + 8 * c;
  unsigned u[4];
#pragma unroll
  for (int q = 0; q < 4; ++q) {
    f16x2 v;
    v.x = (_Float16)ldf_rt(src, base + 2 * q, f32);
    v.y = (_Float16)ldf_rt(src, base + 2 * q + 1, f32);
    u[q] = __builtin_bit_cast(unsigned, v);
  }
  uint4 o; o.x = u[0]; o.y = u[1]; o.z = u[2]; o.w = u[3];
  dst[idx] = o;
}

// ===== MFMA B-fragment packing (gate col n = e*4 + j) =====
__global__ __launch_bounds__(256) void k_packB(const void* src, f16x8* __restrict__ dst,
                                               const void* fprobe) {
  __shared__ int sf;
  if (threadIdx.x == 0) sf = is_f32(fprobe) ? 1 : 0;
  __syncthreads();
  const bool f32 = (sf != 0);
  const int idx = blockIdx.x * 256 + threadIdx.x;  // 0..32767, grid 128
  const int l = idx & 63;
  int rest = idx >> 6;
  const int kt = rest & 7; rest >>= 3;
  const int nt = rest & 15;
  const int w = rest >> 4;
  const int n = 256 * w + nt * 16 + (l & 15);
  const int j = n & 3, e = n >> 2;
  const long base = (long)(j * 256 + e) * 256 + kt * 32 + ((l >> 4) << 3);
  f16x8 v;
#pragma unroll
  for (int q = 0; q < 8; ++q) v[q] = (_Float16)ldf_rt(src, base + q, f32);
  dst[idx] = v;
}

// ===== kernel 1: token gate table -> interleaved fp16x4 tab =====
template <bool F32>
__device__ void tok_table_impl(const void* emb, const float* __restrict__ wT,
                               const void* bih, const void* bhh,
                               f16x4* __restrict__ tabi4, float (*xs)[256]) {
  const int t = threadIdx.x;
  const int v0 = blockIdx.x * 16;
#pragma unroll
  for (int i = 0; i < 16; ++i) xs[i][t] = ldf<F32>(emb, (long)(v0 + i) * EDIM + t);
  __syncthreads();
  float acc[4][16];
#pragma unroll
  for (int j = 0; j < 4; ++j)
#pragma unroll
    for (int i = 0; i < 16; ++i) acc[j][i] = 0.f;
  for (int k4 = 0; k4 < 64; ++k4) {
    float w[4][4];
#pragma unroll
    for (int kk = 0; kk < 4; ++kk)
#pragma unroll
      for (int j = 0; j < 4; ++j)
        w[j][kk] = wT[(size_t)(k4 * 4 + kk) * 1024 + j * 256 + t];
#pragma unroll
    for (int i = 0; i < 16; ++i) {
      float4 h4 = *(const float4*)&xs[i][k4 * 4];
#pragma unroll
      for (int j = 0; j < 4; ++j)
        acc[j][i] = fmaf(h4.x, w[j][0], fmaf(h4.y, w[j][1],
                    fmaf(h4.z, w[j][2], fmaf(h4.w, w[j][3], acc[j][i]))));
    }
  }
  float b[4];
#pragma unroll
  for (int j = 0; j < 4; ++j)
    b[j] = ldf<F32>(bih, j * 256 + t) + ldf<F32>(bhh, j * 256 + t);
#pragma unroll
  for (int i = 0; i < 16; ++i) {
    f16x4 v;
    v.x = (_Float16)(acc[0][i] + b[0]);
    v.y = (_Float16)(acc[1][i] + b[1]);
    v.z = (_Float16)(acc[2][i] + b[2]);
    v.w = (_Float16)(acc[3][i] + b[3]);
    tabi4[(size_t)(v0 + i) * 256 + t] = v;
  }
}

__global__ __launch_bounds__(256) void k_tok_table(
    const void* emb, const float* __restrict__ wT, const void* bih,
    const void* bhh, f16x4* __restrict__ tabi4, const void* fprobe) {
  __shared__ float xs[16][256];
  __shared__ int sf;
  if (threadIdx.x == 0) sf = is_f32(fprobe) ? 1 : 0;
  __syncthreads();
  if (sf) tok_table_impl<true>(emb, wT, bih, bhh, tabi4, xs);
  else    tok_table_impl<false>(emb, wT, bih, bhh, tabi4, xs);
}

// ===== length bucketing: single WG, per-wave histograms =====
__global__ __launch_bounds__(1024) void k_bucket(const int* tlen, int N,
                                                 int* __restrict__ perm,
                                                 const int* iprobe) {
  __shared__ int cnt[16][18];    // per-wave counts / cursors
  __shared__ int wbase[16][18];  // per-wave start within bucket
  __shared__ int base[18];
  const int t = threadIdx.x;
  const int w = t >> 6;
  const bool i64 = (iprobe[1] == 0);
  if (t < 16 * 18) ((int*)cnt)[t] = 0;
  __syncthreads();
  for (int n = t; n < N; n += 1024) {
    int len = ldi_rt(tlen, n, i64);
    len = max(0, min(16, len));
    atomicAdd(&cnt[w][len], 1);
  }
  __syncthreads();
  if (t < 17) {
    int s = 0;
    for (int ww = 0; ww < 16; ++ww) { wbase[ww][t] = s; s += cnt[ww][t]; }
    base[t] = s;   // bucket totals (pre-scan)
  }
  __syncthreads();
  if (t == 0) {
    int s = 0;
    for (int i = 0; i <= 16; ++i) { int c = base[i]; base[i] = s; s += c; }
  }
  __syncthreads();
  if (t < 16 * 18) ((int*)cnt)[t] = 0;   // reuse as per-wave cursors
  __syncthreads();
  for (int n = t; n < N; n += 1024) {
    int len = ldi_rt(tlen, n, i64);
    len = max(0, min(16, len));
    int pos = base[len] + wbase[w][len] + atomicAdd(&cnt[w][len], 1);
    perm[pos] = n;
  }
}

// ===== kernel 2: token LSTM — half-step epilogue, LDS ~26 KB =====
// Wave w's g4 in {0,1} produces ALL 4 gates of elements [64w, 64w+32): a
// self-contained half. Stage 16x132 fp16 per wave, consume (8 cells/lane:
// element l&31, rows 2i+(l>>5)), reuse buffer for g4 in {2,3}.
// Register discipline (r7 lesson): acc+b dead before epilogue; only aF(32)+
// c(16) live across it. Barriers stay 2/step (staging+epilogue own-wave).
struct TokSmemM {
  _Float16 gw4[4][16 * GH_STRIDE];   // 16896 B: per-wave half-gate staging
  _Float16 hA[16 * HA_STRIDE];       // 8448 B: h in MFMA-A layout
  unsigned short tokL[IB][TMAX];     // 512 B (tokens < 2048 fit u16)
  int lenL[IB];
  int nIdx[IB];
};

template <bool I64>
__device__ void tok_mfma_impl(const int* tok32, const int* tlen32,
                              const int* __restrict__ perm,
                              const f16x4* __restrict__ tabi4,
                              const f16x8* __restrict__ pkB,
                              const f16x8* __restrict__ pkBI,
                              const void* bihI, const void* bhhI,
                              float* __restrict__ instrH, float* __restrict__ gx,
                              int N, int do_gx, bool f32, TokSmemM& sm) {
  const int n0 = blockIdx.x * IB, t = threadIdx.x;
  const int w = t >> 6, l = t & 63;
  if (t < IB) {
    int slot = n0 + t;
    int n = (slot < N) ? perm[slot] : -1;
    sm.nIdx[t] = n;
    sm.lenL[t] = (n >= 0) ? ldi<I64>(tlen32, n) : 0;
  }
  for (int idx = t; idx < 16 * HA_STRIDE / 2; idx += 256) ((unsigned*)sm.hA)[idx] = 0;
  __syncthreads();
  {
    int i = t >> 4, s = t & 15;
    int n = sm.nIdx[i];
    sm.tokL[i][s] = (unsigned short)((n >= 0) ? ldi<I64>(tok32, n * TMAX + s) : 0);
  }
  // c[i]   : half A cell (row 2i+rp, elem 64w+eh)
  // c[8+i] : half B cell (row 2i+rp, elem 64w+32+eh)
  float c[IB];
#pragma unroll
  for (int i = 0; i < IB; ++i) c[i] = 0.f;
  __syncthreads();
  int maxlen = 0;
#pragma unroll
  for (int i = 0; i < IB; ++i) maxlen = max(maxlen, sm.lenL[i]);

  const f16x8* Bp = pkB + (size_t)w * (16 * 8 * 64);
  const int aOff = (l & 15) * HA_STRIDE + ((l >> 4) << 3);
  const int m0 = (l >> 4) << 2;
  const int colb = l & 15;
  const int eh = l & 31;    // element within half
  const int rp = l >> 5;    // row parity
  _Float16* gwq = sm.gw4[w];

#define HALF_MFMA(GH, BASEP)                                                          \
  {                                                                                   \
    f32x4 a0 = {0.f, 0.f, 0.f, 0.f}, a1 = a0, a2 = a0, a3 = a0;                       \
    _Pragma("unroll") for (int kt = 0; kt < 8; ++kt) {                                \
      const f16x8* bb = BASEP + ((size_t)((GH) * 4) * 8 + kt) * 64 + l;               \
      f16x8 b0 = bb[0 * 8 * 64];                                                      \
      f16x8 b1 = bb[1 * 8 * 64];                                                      \
      f16x8 b2 = bb[2 * 8 * 64];                                                      \
      f16x8 b3 = bb[3 * 8 * 64];                                                      \
      a0 = __builtin_amdgcn_mfma_f32_16x16x32_f16(aF[kt], b0, a0, 0, 0, 0);           \
      a1 = __builtin_amdgcn_mfma_f32_16x16x32_f16(aF[kt], b1, a1, 0, 0, 0);           \
      a2 = __builtin_amdgcn_mfma_f32_16x16x32_f16(aF[kt], b2, a2, 0, 0, 0);           \
      a3 = __builtin_amdgcn_mfma_f32_16x16x32_f16(aF[kt], b3, a3, 0, 0, 0);           \
    }                                                                                 \
    const int cb = ((GH) & 1) * 64 + colb;                                            \
    _Pragma("unroll") for (int r = 0; r < 4; ++r) {                                   \
      gwq[(m0 + r) * GH_STRIDE + cb + 0 * 16] = (_Float16)a0[r];                      \
      gwq[(m0 + r) * GH_STRIDE + cb + 1 * 16] = (_Float16)a1[r];                      \
      gwq[(m0 + r) * GH_STRIDE + cb + 2 * 16] = (_Float16)a2[r];                      \
      gwq[(m0 + r) * GH_STRIDE + cb + 3 * 16] = (_Float16)a3[r];                      \
    }                                                                                 \
  }

  for (int s = 0; s < maxlen; ++s) {
    f16x8 aF[8];
#pragma unroll
    for (int kt = 0; kt < 8; ++kt)
      aF[kt] = *(const f16x8*)&sm.hA[aOff + kt * 32];
    __syncthreads();   // all waves' aF loaded -> hA writable this step
    // ---- half A: g4 = 0,1 -> gates of elements [64w, 64w+32) ----
    HALF_MFMA(0, Bp)
    HALF_MFMA(1, Bp)
    {
      const int e = 64 * w + eh;
#pragma unroll
      for (int i = 0; i < 8; ++i) {
        const int m = 2 * i + rp;
        if (s < sm.lenL[m]) {
          f16x4 gv = *(const f16x4*)&gwq[m * GH_STRIDE + 4 * eh];
          f16x4 tb = tabi4[(size_t)sm.tokL[m][s] * 256 + e];
          float gi = (float)gv.x + (float)tb.x;
          float gf = (float)gv.y + (float)tb.y;
          float gg = (float)gv.z + (float)tb.z;
          float go = (float)gv.w + (float)tb.w;
          float si = sigm(gi), sf = sigm(gf), tg = tanh_fast(gg), so = sigm(go);
          c[i] = sf * c[i] + si * tg;
          sm.hA[m * HA_STRIDE + e] = (_Float16)(so * tanh_fast(c[i]));
        }
      }
    }
    __builtin_amdgcn_sched_barrier(0);  // keep half-B b-loads out of epilogue A
    // ---- half B: g4 = 2,3 -> gates of elements [64w+32, 64w+64) ----
    HALF_MFMA(2, Bp)
    HALF_MFMA(3, Bp)
    {
      const int e = 64 * w + 32 + eh;
#pragma unroll
      for (int i = 0; i < 8; ++i) {
        const int m = 2 * i + rp;
        if (s < sm.lenL[m]) {
          f16x4 gv = *(const f16x4*)&gwq[m * GH_STRIDE + 4 * eh];
          f16x4 tb = tabi4[(size_t)sm.tokL[m][s] * 256 + e];
          float gi = (float)gv.x + (float)tb.x;
          float gf = (float)gv.y + (float)tb.y;
          float gg = (float)gv.z + (float)tb.z;
          float go = (float)gv.w + (float)tb.w;
          float si = sigm(gi), sf = sigm(gf), tg = tanh_fast(gg), so = sigm(go);
          c[8 + i] = sf * c[8 + i] + si * tg;
          sm.hA[m * HA_STRIDE + e] = (_Float16)(so * tanh_fast(c[8 + i]));
        }
      }
    }
    __syncthreads();   // hA writes visible for next step's aF
  }
  if (!do_gx) {
#pragma unroll
    for (int m = 0; m < IB; ++m) {
      int n = sm.nIdx[m];
      if (n >= 0) instrH[(size_t)n * HDIM + t] = (float)sm.hA[m * HA_STRIDE + t];
    }
  }
  // ===== fused gx phase: gx = hA @ w_ih_ins^T + biases (same half pattern) =====
  if (do_gx) {
    f16x8 aF[8];
#pragma unroll
    for (int kt = 0; kt < 8; ++kt)
      aF[kt] = *(const f16x8*)&sm.hA[aOff + kt * 32];
    const f16x8* BpI = pkBI + (size_t)w * (16 * 8 * 64);
#pragma unroll
    for (int half = 0; half < 2; ++half) {
      if (half == 0) { HALF_MFMA(0, BpI) HALF_MFMA(1, BpI) }
      else           { HALF_MFMA(2, BpI) HALF_MFMA(3, BpI) }
      const int e = 64 * w + 32 * half + eh;
      const float bj0 = ldf_rt(bihI, 0 * 256 + e, f32) + ldf_rt(bhhI, 0 * 256 + e, f32);
      const float bj1 = ldf_rt(bihI, 1 * 256 + e, f32) + ldf_rt(bhhI, 1 * 256 + e, f32);
      const float bj2 = ldf_rt(bihI, 2 * 256 + e, f32) + ldf_rt(bhhI, 2 * 256 + e, f32);
      const float bj3 = ldf_rt(bihI, 3 * 256 + e, f32) + ldf_rt(bhhI, 3 * 256 + e, f32);
#pragma unroll
      for (int i = 0; i < 8; ++i) {
        const int m = 2 * i + rp;
        int n = sm.nIdx[m];
        if (n >= 0) {
          f16x4 gv = *(const f16x4*)&gwq[m * GH_STRIDE + 4 * eh];
          gx[(size_t)n * G4 +       e] = (float)gv.x + bj0;
          gx[(size_t)n * G4 + 256 + e] = (float)gv.y + bj1;
          gx[(size_t)n * G4 + 512 + e] = (float)gv.z + bj2;
          gx[(size_t)n * G4 + 768 + e] = (float)gv.w + bj3;
        }
      }
      __builtin_amdgcn_sched_barrier(0);
    }
  }
#undef HALF_MFMA
}

__global__ __launch_bounds__(256, 2) void k_tok_lstm(
    const int* tok32, const int* tlen32, const int* __restrict__ perm,
    const f16x4* __restrict__ tabi4, const f16x8* __restrict__ pkB,
    const f16x8* __restrict__ pkBI, const void* bihI, const void* bhhI,
    float* __restrict__ instrH, float* __restrict__ gx, int N, int do_gx,
    const int* iprobe, const void* fprobe) {
  __shared__ TokSmemM sm;
  __shared__ int sfl;
  if (threadIdx.x == 0)
    sfl = ((iprobe[1] == 0) ? 1 : 0) | (is_f32(fprobe) ? 2 : 0);
  __syncthreads();
  const bool f32 = (sfl & 2) != 0;
  if (sfl & 1) tok_mfma_impl<true >(tok32, tlen32, perm, tabi4, pkB, pkBI, bihI, bhhI, instrH, gx, N, do_gx, f32, sm);
  else         tok_mfma_impl<false>(tok32, tlen32, perm, tabi4, pkB, pkBI, bihI, bhhI, instrH, gx, N, do_gx, f32, sm);
}

// ===== kernel 3b: instruction-LSTM — weights RESIDENT in regs+LDS =====
#define RCH 24   // chunks in registers
#define LCH 8    // chunks in LDS
struct InsSmem {
  uint4 wL[LCH][1024];   // 128 KB resident weights (chunks RCH..31)
  float gL[1024];        // 4 KB gates
  f16x2 hL2[128];        // 512 B h (fp16)
  float red[256];
};

template <bool F32, bool I64>
__device__ void ins_rec_impl(const int* ilen32, const int* bnd32,
                             const float* __restrict__ gx,
                             const uint4* __restrict__ pk,
                             const void* wlin, const void* blin,
                             float* __restrict__ out, int B, InsSmem& sm) {
  const int b = blockIdx.x, t = threadIdx.x;
  const int j = t >> 8, rr = t & 255;
  const int len = ldi<I64>(ilen32, b);
  const long n0 = (long)ldi<I64>(bnd32, b);
#pragma unroll
  for (int cc = 0; cc < LCH; ++cc)
    sm.wL[cc][t] = pk[((RCH + cc) * 4 + j) * 256 + rr];
  uint4 wr[RCH];
#pragma unroll
  for (int cg = 0; cg < RCH; ++cg)
    wr[cg] = pk[(cg * 4 + j) * 256 + rr];
  if (t < 128) {
    f16x2 z; z.x = (_Float16)0.f; z.y = (_Float16)0.f;
    sm.hL2[t] = z;
  }
  float c = 0.f, h = 0.f;
  __syncthreads();

  for (int m = 0; m < len; ++m) {
    float g0 = 0.f, g1 = 0.f, g2 = 0.f, g3 = 0.f;
    if (t < 256) {
      const float* gp = gx + (size_t)(n0 + m) * G4;
      g0 = gp[t]; g1 = gp[256 + t]; g2 = gp[512 + t]; g3 = gp[768 + t];
    }
    float a0 = 0.f, a1 = 0.f;
#pragma unroll
    for (int cg = 0; cg < RCH; ++cg) {
      float4 hv = ((const float4*)sm.hL2)[cg];
      if (cg & 1) a1 = dot8h(wr[cg], hv, a1);
      else        a0 = dot8h(wr[cg], hv, a0);
    }
#pragma unroll
    for (int cc = 0; cc < LCH; ++cc) {
      float4 hv = ((const float4*)sm.hL2)[RCH + cc];
      if (cc & 1) a1 = dot8h(sm.wL[cc][t], hv, a1);
      else        a0 = dot8h(sm.wL[cc][t], hv, a0);
    }
    sm.gL[t] = a0 + a1;
    __syncthreads();
    if (t < 256) {
      float gi = g0 + sm.gL[t];
      float gf = g1 + sm.gL[256 + t];
      float gg = g2 + sm.gL[512 + t];
      float go = g3 + sm.gL[768 + t];
      float si = sigm(gi), sf = sigm(gf), tg = tanh_fast(gg), so = sigm(go);
      c = sf * c + si * tg;
      h = so * tanh_fast(c);
      ((_Float16*)sm.hL2)[t] = (_Float16)h;
    }
    __syncthreads();
  }
  if (t < 256) sm.red[t] = h * ldf<F32>(wlin, t);
  __syncthreads();
  for (int st = 128; st > 0; st >>= 1) {
    if (t < st) sm.red[t] += sm.red[t + st];
    __syncthreads();
  }
  if (t == 0) out[b] = sm.red[0] + ldf<F32>(blin, 0);
}

__global__ __launch_bounds__(1024) void k_ins_rec(
    const int* ilen32, const int* bnd32, const float* __restrict__ gx,
    const uint4* __restrict__ pk, const void* wlin, const void* blin,
    float* __restrict__ out, int B, const void* fprobe, const int* iprobe) {
  __shared__ InsSmem sm;
  __shared__ int sfl;
  if (threadIdx.x == 0)
    sfl = (is_f32(fprobe) ? 1 : 0) | ((iprobe[1] == 0) ? 2 : 0);
  __syncthreads();
  const int fl = sfl;
  if (fl == 0)      ins_rec_impl<false, false>(ilen32, bnd32, gx, pk, wlin, blin, out, B, sm);
  else if (fl == 1) ins_rec_impl<true,  false>(ilen32, bnd32, gx, pk, wlin, blin, out, B, sm);
  else if (fl == 2) ins_rec_impl<false, true >(ilen32, bnd32, gx, pk, wlin, blin, out, B, sm);
  else              ins_rec_impl<true,  true >(ilen32, bnd32, gx, pk, wlin, blin, out, B, sm);
}

// ===== fallback (no gx workspace): fp32, 4 blocks per WG =====
#define IBB 4
struct InsSmemFB {
  float hL[IBB][HDIM];
  float xL[IBB][HDIM];
  float gL[IBB][G4];
};

template <bool F32, bool I64>
__device__ void ins_fb_impl(const int* ilen32, const int* bnd32,
                            const float* __restrict__ instrH,
                            const float* __restrict__ wTih,
                            const float* __restrict__ wThh,
                            const void* bih, const void* bhh,
                            const void* wlin, const void* blin,
                            float* __restrict__ out, int B, InsSmemFB& sm) {
  const int wg = blockIdx.x, t = threadIdx.x;
  const int myblk = t >> 8, myelem = t & 255;
  int len[IBB], n0[IBB];
#pragma unroll
  for (int i = 0; i < IBB; ++i) {
    int b = wg * IBB + i;
    len[i] = (b < B) ? ldi<I64>(ilen32, b) : 0;
    n0[i]  = (b < B) ? ldi<I64>(bnd32, b) : 0;
  }
  float c = 0.f;
  sm.hL[myblk][myelem] = 0.f;
  float bias_r = ldf<F32>(bih, t) + ldf<F32>(bhh, t);
  __syncthreads();
  int maxlen = 0;
#pragma unroll
  for (int i = 0; i < IBB; ++i) maxlen = max(maxlen, len[i]);
  for (int m = 0; m < maxlen; ++m) {
    unsigned act = 0;
#pragma unroll
    for (int i = 0; i < IBB; ++i) if (m < len[i]) act |= (1u << i);
    if (m < len[myblk])
      sm.xL[myblk][myelem] = instrH[(size_t)(n0[myblk] + m) * HDIM + myelem];
    __syncthreads();
    float a[IBB];
#pragma unroll
    for (int i = 0; i < IBB; ++i) a[i] = (act & (1u << i)) ? bias_r : 0.f;
    for (int k4 = 0; k4 < 64; ++k4) {
      float w0 = wThh[(size_t)(k4 * 4 + 0) * 1024 + t];
      float w1 = wThh[(size_t)(k4 * 4 + 1) * 1024 + t];
      float w2 = wThh[(size_t)(k4 * 4 + 2) * 1024 + t];
      float w3 = wThh[(size_t)(k4 * 4 + 3) * 1024 + t];
      float u0 = wTih[(size_t)(k4 * 4 + 0) * 1024 + t];
      float u1 = wTih[(size_t)(k4 * 4 + 1) * 1024 + t];
      float u2 = wTih[(size_t)(k4 * 4 + 2) * 1024 + t];
      float u3 = wTih[(size_t)(k4 * 4 + 3) * 1024 + t];
#pragma unroll
      for (int i = 0; i < IBB; ++i) {
        if (!(act & (1u << i))) continue;
        float4 h4 = *(const float4*)&sm.hL[i][k4 * 4];
        float4 x4 = *(const float4*)&sm.xL[i][k4 * 4];
        a[i] = fmaf(h4.x, w0, fmaf(h4.y, w1, fmaf(h4.z, w2, fmaf(h4.w, w3, a[i]))));
        a[i] = fmaf(x4.x, u0, fmaf(x4.y, u1, fmaf(x4.z, u2, fmaf(x4.w, u3, a[i]))));
      }
    }
#pragma unroll
    for (int i = 0; i < IBB; ++i)
      if (act & (1u << i)) sm.gL[i][t] = a[i];
    __syncthreads();
    if (m < len[myblk]) {
      float si = sigm(sm.gL[myblk][myelem]);
      float sf = sigm(sm.gL[myblk][256 + myelem]);
      float tg = tanh_fast(sm.gL[myblk][512 + myelem]);
      float so = sigm(sm.gL[myblk][768 + myelem]);
      c = sf * c + si * tg;
      sm.hL[myblk][myelem] = so * tanh_fast(c);
    }
    __syncthreads();
  }
  sm.gL[myblk][myelem] = sm.hL[myblk][myelem] * ldf<F32>(wlin, myelem);
  __syncthreads();
  for (int st = 128; st > 0; st >>= 1) {
    if (myelem < st) sm.gL[myblk][myelem] += sm.gL[myblk][myelem + st];
    __syncthreads();
  }
  if (myelem == 0 && wg * IBB + myblk < B)
    out[wg * IBB + myblk] = sm.gL[myblk][0] + ldf<F32>(blin, 0);
}

__global__ __launch_bounds__(1024) void k_ins_fb(
    const int* ilen32, const int* bnd32, const float* __restrict__ instrH,
    const float* __restrict__ wTih, const float* __restrict__ wThh,
    const void* bih, const void* bhh, const void* wlin, const void* blin,
    float* __restrict__ out, int B, const void* fprobe, const int* iprobe) {
  __shared__ InsSmemFB sm;
  __shared__ int sfl;
  if (threadIdx.x == 0)
    sfl = (is_f32(fprobe) ? 1 : 0) | ((iprobe[1] == 0) ? 2 : 0);
  __syncthreads();
  const int fl = sfl;
  if (fl == 0)      ins_fb_impl<false, false>(ilen32, bnd32, instrH, wTih, wThh, bih, bhh, wlin, blin, out, B, sm);
  else if (fl == 1) ins_fb_impl<true,  false>(ilen32, bnd32, instrH, wTih, wThh, bih, bhh, wlin, blin, out, B, sm);
  else if (fl == 2) ins_fb_impl<false, true >(ilen32, bnd32, instrH, wTih, wThh, bih, bhh, wlin, blin, out, B, sm);
  else              ins_fb_impl<true,  true >(ilen32, bnd32, instrH, wTih, wThh, bih, bhh, wlin, blin, out, B, sm);
}

extern "C" void kernel_launch(void* const* d_in, const int* in_sizes, int n_in,
                              void* d_out, int out_size, void* d_ws, size_t ws_size,
                              hipStream_t stream) {
  const int N = in_sizes[1];   // total instructions
  const int B = in_sizes[2];   // basic blocks

  // ---- workspace layout (float units) ----
  float* ws = (float*)d_ws;
  size_t off = 0;
  f16x4* tabi4 = (f16x4*)(ws + off); off += (size_t)VSZ * G4 / 2;  // 4 MB fp16
  float* instrH   = ws + off; off += (size_t)N * HDIM;
  float* wT_ihI   = ws + off; off += 262144;               // w_ih_ins^T fp32 (fb)
  float* wT_hhI   = ws + off; off += 262144;               // w_hh_ins^T fp32 (fb)
  float* wT_ihT   = ws + off; off += 262144;               // w_ih_tok^T fp32
  f16x8* pkB_tok  = (f16x8*)(ws + off); off += 131072;     // MFMA B-frag w_hh_tok
  f16x8* pkB_ins  = (f16x8*)(ws + off); off += 131072;     // MFMA B-frag w_ih_ins (fused gx)
  uint4* pk_ins   = (uint4*)(ws + off); off += 131072;     // row-gang fp16 w_hh_ins
  int*   permI    = (int*)(ws + off);
  off += ((size_t)N + 15) & ~(size_t)15;
  float* gx       = ws + off;
  const size_t need_gx = (off + (size_t)N * G4) * sizeof(float);
  const bool has_gx = (ws_size >= need_gx);

  const void* fprobe = d_in[5];              // w_ih_tok
  const int*  iprobe = (const int*)d_in[1];  // token_lengths

  hipLaunchKernelGGL(k_transp, dim3(32, 8), dim3(256), 0, stream, d_in[5], wT_ihT, fprobe);
  hipLaunchKernelGGL(k_transp, dim3(32, 8), dim3(256), 0, stream, d_in[9], wT_ihI, fprobe);
  hipLaunchKernelGGL(k_transp, dim3(32, 8), dim3(256), 0, stream, d_in[10], wT_hhI, fprobe);
  hipLaunchKernelGGL(k_packB, dim3(128), dim3(256), 0, stream, d_in[6], pkB_tok, fprobe);
  hipLaunchKernelGGL(k_packB, dim3(128), dim3(256), 0, stream, d_in[9], pkB_ins, fprobe);
  hipLaunchKernelGGL(k_pack, dim3(128), dim3(256), 0, stream, d_in[10], pk_ins, fprobe);

  hipLaunchKernelGGL(k_tok_table, dim3(VSZ / 16), dim3(256), 0, stream,
                     d_in[4], wT_ihT, d_in[7], d_in[8], tabi4, fprobe);
  hipLaunchKernelGGL(k_bucket, dim3(1), dim3(1024), 0, stream,
                     (const int*)d_in[1], N, permI, iprobe);
  hipLaunchKernelGGL(k_tok_lstm, dim3((N + IB - 1) / IB), dim3(256), 0, stream,
                     (const int*)d_in[0], (const int*)d_in[1], permI, tabi4,
                     pkB_tok, pkB_ins, d_in[11], d_in[12], instrH, gx, N,
                     has_gx ? 1 : 0, iprobe, fprobe);
  if (has_gx) {
    hipLaunchKernelGGL(k_ins_rec, dim3(B), dim3(1024), 0, stream,
                       (const int*)d_in[2], (const int*)d_in[3], gx, pk_ins,
                       d_in[13], d_in[14], (float*)d_out, B, fprobe, iprobe);
  } else {
    hipLaunchKernelGGL(k_ins_fb, dim3((B + IBB - 1) / IBB), dim3(1024), 0, stream,
                       (const int*)d_in[2], (const int*)d_in[3], instrH,
                       wT_ihI, wT_hhI, d_in[11], d_in[12], d_in[13], d_in[14],
                       (float*)d_out, B, fprobe, iprobe);
  }
}

// Round 11
// 696.913 us; speedup vs baseline: 2.0792x; 2.0792x over previous
//
#include <hip/hip_runtime.h>
#include <hip/hip_bf16.h>
#include <math.h>

#define VSZ 2048
#define EDIM 256
#define HDIM 256
#define G4 1024   // 4*H
#define TMAX 16
#define IB 16     // instructions per workgroup in token-LSTM (MFMA M=16)

typedef _Float16 f16x2 __attribute__((ext_vector_type(2)));
typedef _Float16 f16x4 __attribute__((ext_vector_type(4)));
typedef _Float16 f16x8 __attribute__((ext_vector_type(8)));
typedef float f32x4 __attribute__((ext_vector_type(4)));

#define HA_STRIDE 264    // fp16 elems per hA row (256 + 8 pad)
#define GWH_STRIDE 264   // fp16 elems per gate-staging row (256 + 8 pad)

// ---- fast activations: v_exp_f32 / v_rcp_f32 based (verified rounds 2-9) ----
__device__ __forceinline__ float fexp2(float x) {
#if defined(__has_builtin) && __has_builtin(__builtin_amdgcn_exp2f)
  return __builtin_amdgcn_exp2f(x);
#else
  return exp2f(x);
#endif
}
__device__ __forceinline__ float frcp(float x) {
#if defined(__has_builtin) && __has_builtin(__builtin_amdgcn_rcpf)
  return __builtin_amdgcn_rcpf(x);
#else
  return 1.0f / x;
#endif
}
__device__ __forceinline__ float sigm(float x) {
  return frcp(1.0f + fexp2(x * -1.44269504f));
}
__device__ __forceinline__ float tanh_fast(float x) {
  float t = fexp2(fminf(x, 15.0f) * 2.88539008f);
  return (t - 1.0f) * frcp(t + 1.0f);
}

__device__ __forceinline__ float fdot2(f16x2 a, f16x2 b, float c) {
#if defined(__has_builtin) && __has_builtin(__builtin_amdgcn_fdot2)
  return __builtin_amdgcn_fdot2(a, b, c, false);
#else
  return c + (float)a.x * (float)b.x + (float)a.y * (float)b.y;
#endif
}

__device__ __forceinline__ float dot8h(uint4 w, float4 hv, float acc) {
  f16x2 h0 = __builtin_bit_cast(f16x2, hv.x);
  f16x2 h1 = __builtin_bit_cast(f16x2, hv.y);
  f16x2 h2 = __builtin_bit_cast(f16x2, hv.z);
  f16x2 h3 = __builtin_bit_cast(f16x2, hv.w);
  f16x2 w0 = __builtin_bit_cast(f16x2, w.x);
  f16x2 w1 = __builtin_bit_cast(f16x2, w.y);
  f16x2 w2 = __builtin_bit_cast(f16x2, w.z);
  f16x2 w3 = __builtin_bit_cast(f16x2, w.w);
  return fdot2(h3, w3, fdot2(h2, w2, fdot2(h1, w1, fdot2(h0, w0, acc))));
}

// ---- dtype probes ----
__device__ __forceinline__ bool is_f32(const void* w) {
  const unsigned short* p = (const unsigned short*)w;
  int pl = 0;
#pragma unroll
  for (int i = 0; i < 64; ++i) {
    unsigned e = (p[2 * i] >> 7) & 0xFF;
    pl += (e >= 113 && e <= 122) ? 1 : 0;
  }
  return pl < 48;
}

// ---- typed loads ----
template <bool F32>
__device__ __forceinline__ float ldf(const void* p, long j) {
  if (F32) return ((const float*)p)[j];
  return __uint_as_float(((unsigned)((const unsigned short*)p)[j]) << 16);
}
__device__ __forceinline__ float ldf_rt(const void* p, long j, bool f32) {
  if (f32) return ((const float*)p)[j];
  return __uint_as_float(((unsigned)((const unsigned short*)p)[j]) << 16);
}
template <bool I64>
__device__ __forceinline__ int ldi(const int* p, int j) {
  return I64 ? p[2 * j] : p[j];
}
__device__ __forceinline__ int ldi_rt(const int* p, int j, bool i64) {
  return i64 ? p[2 * j] : p[j];
}

// ===== fp32 transpose: dst[k*1024 + r] = src[r*256 + k] =====
__global__ __launch_bounds__(256) void k_transp(const void* src, float* __restrict__ dst,
                                                const void* fprobe) {
  __shared__ float tile[32][33];
  __shared__ int sf;
  if (threadIdx.x == 0) sf = is_f32(fprobe) ? 1 : 0;
  __syncthreads();
  const bool f32 = (sf != 0);
  const int tx = threadIdx.x & 31, ty = threadIdx.x >> 5;
  const int r0 = blockIdx.x * 32, c0 = blockIdx.y * 32;
#pragma unroll
  for (int q = 0; q < 4; ++q) {
    int rr = ty + q * 8;
    tile[rr][tx] = ldf_rt(src, (long)(r0 + rr) * 256 + (c0 + tx), f32);
  }
  __syncthreads();
#pragma unroll
  for (int q = 0; q < 4; ++q) {
    int cc = ty + q * 8;
    dst[(size_t)(c0 + cc) * 1024 + (r0 + tx)] = tile[tx][cc];
  }
}

// ===== fp16 weight packing (row-gang layout for k_ins_rec) =====
__global__ __launch_bounds__(256) void k_pack(const void* src, uint4* __restrict__ dst,
                                              const void* fprobe) {
  __shared__ int sf;
  if (threadIdx.x == 0) sf = is_f32(fprobe) ? 1 : 0;
  __syncthreads();
  const bool f32 = (sf != 0);
  const int idx = blockIdx.x * 256 + threadIdx.x;  // grid 128
  const int rr = idx & 255, j = (idx >> 8) & 3, c = idx >> 10;
  const long base = (long)(j * 256 + rr) * 256 + 8 * c;
  unsigned u[4];
#pragma unroll
  for (int q = 0; q < 4; ++q) {
    f16x2 v;
    v.x = (_Float16)ldf_rt(src, base + 2 * q, f32);
    v.y = (_Float16)ldf_rt(src, base + 2 * q + 1, f32);
    u[q] = __builtin_bit_cast(unsigned, v);
  }
  uint4 o; o.x = u[0]; o.y = u[1]; o.z = u[2]; o.w = u[3];
  dst[idx] = o;
}

// ===== MFMA B-fragment packing (gate col n = e*4 + j) =====
__global__ __launch_bounds__(256) void k_packB(const void* src, f16x8* __restrict__ dst,
                                               const void* fprobe) {
  __shared__ int sf;
  if (threadIdx.x == 0) sf = is_f32(fprobe) ? 1 : 0;
  __syncthreads();
  const bool f32 = (sf != 0);
  const int idx = blockIdx.x * 256 + threadIdx.x;  // 0..32767, grid 128
  const int l = idx & 63;
  int rest = idx >> 6;
  const int kt = rest & 7; rest >>= 3;
  const int nt = rest & 15;
  const int w = rest >> 4;
  const int n = 256 * w + nt * 16 + (l & 15);
  const int j = n & 3, e = n >> 2;
  const long base = (long)(j * 256 + e) * 256 + kt * 32 + ((l >> 4) << 3);
  f16x8 v;
#pragma unroll
  for (int q = 0; q < 8; ++q) v[q] = (_Float16)ldf_rt(src, base + q, f32);
  dst[idx] = v;
}

// ===== kernel 1: token gate table -> interleaved fp16x4 tab =====
template <bool F32>
__device__ void tok_table_impl(const void* emb, const float* __restrict__ wT,
                               const void* bih, const void* bhh,
                               f16x4* __restrict__ tabi4, float (*xs)[256]) {
  const int t = threadIdx.x;
  const int v0 = blockIdx.x * 16;
#pragma unroll
  for (int i = 0; i < 16; ++i) xs[i][t] = ldf<F32>(emb, (long)(v0 + i) * EDIM + t);
  __syncthreads();
  float acc[4][16];
#pragma unroll
  for (int j = 0; j < 4; ++j)
#pragma unroll
    for (int i = 0; i < 16; ++i) acc[j][i] = 0.f;
  for (int k4 = 0; k4 < 64; ++k4) {
    float w[4][4];
#pragma unroll
    for (int kk = 0; kk < 4; ++kk)
#pragma unroll
      for (int j = 0; j < 4; ++j)
        w[j][kk] = wT[(size_t)(k4 * 4 + kk) * 1024 + j * 256 + t];
#pragma unroll
    for (int i = 0; i < 16; ++i) {
      float4 h4 = *(const float4*)&xs[i][k4 * 4];
#pragma unroll
      for (int j = 0; j < 4; ++j)
        acc[j][i] = fmaf(h4.x, w[j][0], fmaf(h4.y, w[j][1],
                    fmaf(h4.z, w[j][2], fmaf(h4.w, w[j][3], acc[j][i]))));
    }
  }
  float b[4];
#pragma unroll
  for (int j = 0; j < 4; ++j)
    b[j] = ldf<F32>(bih, j * 256 + t) + ldf<F32>(bhh, j * 256 + t);
#pragma unroll
  for (int i = 0; i < 16; ++i) {
    f16x4 v;
    v.x = (_Float16)(acc[0][i] + b[0]);
    v.y = (_Float16)(acc[1][i] + b[1]);
    v.z = (_Float16)(acc[2][i] + b[2]);
    v.w = (_Float16)(acc[3][i] + b[3]);
    tabi4[(size_t)(v0 + i) * 256 + t] = v;
  }
}

__global__ __launch_bounds__(256) void k_tok_table(
    const void* emb, const float* __restrict__ wT, const void* bih,
    const void* bhh, f16x4* __restrict__ tabi4, const void* fprobe) {
  __shared__ float xs[16][256];
  __shared__ int sf;
  if (threadIdx.x == 0) sf = is_f32(fprobe) ? 1 : 0;
  __syncthreads();
  if (sf) tok_table_impl<true>(emb, wT, bih, bhh, tabi4, xs);
  else    tok_table_impl<false>(emb, wT, bih, bhh, tabi4, xs);
}

// ===== length bucketing: single WG, per-wave histograms =====
__global__ __launch_bounds__(1024) void k_bucket(const int* tlen, int N,
                                                 int* __restrict__ perm,
                                                 const int* iprobe) {
  __shared__ int cnt[16][18];    // per-wave counts / cursors
  __shared__ int wbase[16][18];  // per-wave start within bucket
  __shared__ int base[18];
  const int t = threadIdx.x;
  const int w = t >> 6;
  const bool i64 = (iprobe[1] == 0);
  if (t < 16 * 18) ((int*)cnt)[t] = 0;
  __syncthreads();
  for (int n = t; n < N; n += 1024) {
    int len = ldi_rt(tlen, n, i64);
    len = max(0, min(16, len));
    atomicAdd(&cnt[w][len], 1);
  }
  __syncthreads();
  if (t < 17) {
    int s = 0;
    for (int ww = 0; ww < 16; ++ww) { wbase[ww][t] = s; s += cnt[ww][t]; }
    base[t] = s;   // bucket totals (pre-scan)
  }
  __syncthreads();
  if (t == 0) {
    int s = 0;
    for (int i = 0; i <= 16; ++i) { int c = base[i]; base[i] = s; s += c; }
  }
  __syncthreads();
  if (t < 16 * 18) ((int*)cnt)[t] = 0;   // reuse as per-wave cursors
  __syncthreads();
  for (int n = t; n < N; n += 1024) {
    int len = ldi_rt(tlen, n, i64);
    len = max(0, min(16, len));
    int pos = base[len] + wbase[w][len] + atomicAdd(&cnt[w][len], 1);
    perm[pos] = n;
  }
}

// ===== kernel 2: token LSTM — round-8 shape EXACT (358us, VGPR 76 proven) =====
// r7/r9 lesson (firm after 3 datapoints): any structure keeping MFMA operands
// live across an epilogue exceeds the 128-VGPR cap and spills catastrophically.
// Only the strictly phase-sequential shape (MFMA -> acc/b/aF dead -> epilogue)
// stays under; do not interleave.
struct TokSmemM {
  _Float16 gateW[4][16 * GWH_STRIDE];  // 33792 B: per-wave D staging (fp16)
  _Float16 hA[16 * HA_STRIDE];         // 8448 B: h in MFMA-A layout (fp16)
  int tokL[IB][TMAX];
  int lenL[IB];
  int nIdx[IB];
};

template <bool I64>
__device__ void tok_mfma_impl(const int* tok32, const int* tlen32,
                              const int* __restrict__ perm,
                              const f16x4* __restrict__ tabi4,
                              const f16x8* __restrict__ pkB,
                              const f16x8* __restrict__ pkBI,
                              const void* bihI, const void* bhhI,
                              float* __restrict__ instrH, float* __restrict__ gx,
                              int N, int do_gx, bool f32, TokSmemM& sm) {
  const int n0 = blockIdx.x * IB, t = threadIdx.x;
  const int w = t >> 6, l = t & 63;
  if (t < IB) {
    int slot = n0 + t;
    int n = (slot < N) ? perm[slot] : -1;
    sm.nIdx[t] = n;
    sm.lenL[t] = (n >= 0) ? ldi<I64>(tlen32, n) : 0;
  }
  for (int idx = t; idx < 16 * HA_STRIDE / 2; idx += 256) ((unsigned*)sm.hA)[idx] = 0;
  __syncthreads();
  {
    int i = t >> 4, s = t & 15;
    int n = sm.nIdx[i];
    sm.tokL[i][s] = (n >= 0) ? ldi<I64>(tok32, n * TMAX + s) : 0;
  }
  float c[IB];
#pragma unroll
  for (int i = 0; i < IB; ++i) c[i] = 0.f;
  __syncthreads();
  int maxlen = 0;
#pragma unroll
  for (int i = 0; i < IB; ++i) maxlen = max(maxlen, sm.lenL[i]);

  const f16x8* Bp = pkB + (size_t)w * (16 * 8 * 64);
  const int aOff = (l & 15) * HA_STRIDE + ((l >> 4) << 3);
  const int m0 = (l >> 4) << 2;
  _Float16* gw = sm.gateW[w];

  for (int s = 0; s < maxlen; ++s) {
    f16x8 aF[8];
#pragma unroll
    for (int kt = 0; kt < 8; ++kt)
      aF[kt] = *(const f16x8*)&sm.hA[aOff + kt * 32];
    // unroll 2: overlap two MFMA chains without spilling (96 VGPR proven)
#pragma unroll 2
    for (int g4 = 0; g4 < 4; ++g4) {
      f32x4 a0 = {0.f, 0.f, 0.f, 0.f}, a1 = a0, a2 = a0, a3 = a0;
#pragma unroll
      for (int kt = 0; kt < 8; ++kt) {
        const f16x8* bb = Bp + ((size_t)(g4 * 4) * 8 + kt) * 64 + l;
        f16x8 b0 = bb[0 * 8 * 64];
        f16x8 b1 = bb[1 * 8 * 64];
        f16x8 b2 = bb[2 * 8 * 64];
        f16x8 b3 = bb[3 * 8 * 64];
        a0 = __builtin_amdgcn_mfma_f32_16x16x32_f16(aF[kt], b0, a0, 0, 0, 0);
        a1 = __builtin_amdgcn_mfma_f32_16x16x32_f16(aF[kt], b1, a1, 0, 0, 0);
        a2 = __builtin_amdgcn_mfma_f32_16x16x32_f16(aF[kt], b2, a2, 0, 0, 0);
        a3 = __builtin_amdgcn_mfma_f32_16x16x32_f16(aF[kt], b3, a3, 0, 0, 0);
      }
      const int colb = (l & 15);
#pragma unroll
      for (int r = 0; r < 4; ++r) {
        gw[(m0 + r) * GWH_STRIDE + (g4 * 4 + 0) * 16 + colb] = (_Float16)a0[r];
        gw[(m0 + r) * GWH_STRIDE + (g4 * 4 + 1) * 16 + colb] = (_Float16)a1[r];
        gw[(m0 + r) * GWH_STRIDE + (g4 * 4 + 2) * 16 + colb] = (_Float16)a2[r];
        gw[(m0 + r) * GWH_STRIDE + (g4 * 4 + 3) * 16 + colb] = (_Float16)a3[r];
      }
    }
    __syncthreads();
    // epilogue: FULL unroll, fp16 gate slice read (8B, 2-way bank = free)
#pragma unroll
    for (int m = 0; m < IB; ++m) {
      if (s < sm.lenL[m]) {
        f16x4 gv = *(const f16x4*)&gw[m * GWH_STRIDE + 4 * l];
        f16x4 tb = tabi4[(size_t)sm.tokL[m][s] * 256 + t];
        float gi = (float)gv.x + (float)tb.x;
        float gf = (float)gv.y + (float)tb.y;
        float gg = (float)gv.z + (float)tb.z;
        float go = (float)gv.w + (float)tb.w;
        float si = sigm(gi), sf = sigm(gf), tg = tanh_fast(gg), so = sigm(go);
        c[m] = sf * c[m] + si * tg;
        sm.hA[m * HA_STRIDE + t] = (_Float16)(so * tanh_fast(c[m]));
      }
    }
    __syncthreads();
  }
#pragma unroll
  for (int m = 0; m < IB; ++m) {
    int n = sm.nIdx[m];
    if (n >= 0) instrH[(size_t)n * HDIM + t] = (float)sm.hA[m * HA_STRIDE + t];
  }
  // ===== fused gx phase: gx = hA @ w_ih_ins^T + biases (fp16 staging) =====
  if (do_gx) {
    f16x8 aF[8];
#pragma unroll
    for (int kt = 0; kt < 8; ++kt)
      aF[kt] = *(const f16x8*)&sm.hA[aOff + kt * 32];
    const f16x8* BpI = pkBI + (size_t)w * (16 * 8 * 64);
#pragma unroll 2
    for (int g4 = 0; g4 < 4; ++g4) {
      f32x4 a0 = {0.f, 0.f, 0.f, 0.f}, a1 = a0, a2 = a0, a3 = a0;
#pragma unroll
      for (int kt = 0; kt < 8; ++kt) {
        const f16x8* bb = BpI + ((size_t)(g4 * 4) * 8 + kt) * 64 + l;
        f16x8 b0 = bb[0 * 8 * 64];
        f16x8 b1 = bb[1 * 8 * 64];
        f16x8 b2 = bb[2 * 8 * 64];
        f16x8 b3 = bb[3 * 8 * 64];
        a0 = __builtin_amdgcn_mfma_f32_16x16x32_f16(aF[kt], b0, a0, 0, 0, 0);
        a1 = __builtin_amdgcn_mfma_f32_16x16x32_f16(aF[kt], b1, a1, 0, 0, 0);
        a2 = __builtin_amdgcn_mfma_f32_16x16x32_f16(aF[kt], b2, a2, 0, 0, 0);
        a3 = __builtin_amdgcn_mfma_f32_16x16x32_f16(aF[kt], b3, a3, 0, 0, 0);
      }
      const int colb = (l & 15);
#pragma unroll
      for (int r = 0; r < 4; ++r) {
        gw[(m0 + r) * GWH_STRIDE + (g4 * 4 + 0) * 16 + colb] = (_Float16)a0[r];
        gw[(m0 + r) * GWH_STRIDE + (g4 * 4 + 1) * 16 + colb] = (_Float16)a1[r];
        gw[(m0 + r) * GWH_STRIDE + (g4 * 4 + 2) * 16 + colb] = (_Float16)a2[r];
        gw[(m0 + r) * GWH_STRIDE + (g4 * 4 + 3) * 16 + colb] = (_Float16)a3[r];
      }
    }
    __syncthreads();
    const float bj0 = ldf_rt(bihI, 0 * 256 + t, f32) + ldf_rt(bhhI, 0 * 256 + t, f32);
    const float bj1 = ldf_rt(bihI, 1 * 256 + t, f32) + ldf_rt(bhhI, 1 * 256 + t, f32);
    const float bj2 = ldf_rt(bihI, 2 * 256 + t, f32) + ldf_rt(bhhI, 2 * 256 + t, f32);
    const float bj3 = ldf_rt(bihI, 3 * 256 + t, f32) + ldf_rt(bhhI, 3 * 256 + t, f32);
#pragma unroll
    for (int m = 0; m < IB; ++m) {
      int n = sm.nIdx[m];
      if (n >= 0) {
        f16x4 gv = *(const f16x4*)&gw[m * GWH_STRIDE + 4 * l];
        gx[(size_t)n * G4 +       t] = (float)gv.x + bj0;
        gx[(size_t)n * G4 + 256 + t] = (float)gv.y + bj1;
        gx[(size_t)n * G4 + 512 + t] = (float)gv.z + bj2;
        gx[(size_t)n * G4 + 768 + t] = (float)gv.w + bj3;
      }
    }
  }
}

__global__ __launch_bounds__(256, 2) void k_tok_lstm(
    const int* tok32, const int* tlen32, const int* __restrict__ perm,
    const f16x4* __restrict__ tabi4, const f16x8* __restrict__ pkB,
    const f16x8* __restrict__ pkBI, const void* bihI, const void* bhhI,
    float* __restrict__ instrH, float* __restrict__ gx, int N, int do_gx,
    const int* iprobe, const void* fprobe) {
  __shared__ TokSmemM sm;
  __shared__ int sfl;
  if (threadIdx.x == 0)
    sfl = ((iprobe[1] == 0) ? 1 : 0) | (is_f32(fprobe) ? 2 : 0);
  __syncthreads();
  const bool f32 = (sfl & 2) != 0;
  if (sfl & 1) tok_mfma_impl<true >(tok32, tlen32, perm, tabi4, pkB, pkBI, bihI, bhhI, instrH, gx, N, do_gx, f32, sm);
  else         tok_mfma_impl<false>(tok32, tlen32, perm, tabi4, pkB, pkBI, bihI, bhhI, instrH, gx, N, do_gx, f32, sm);
}

// ===== kernel 3b: instruction-LSTM — weights resident, gx prefetch pipeline =====
#define RCH 24   // chunks in registers
#define LCH 8    // chunks in LDS
struct InsSmem {
  uint4 wL[LCH][1024];   // 128 KB resident weights (chunks RCH..31)
  float gL[1024];        // 4 KB gates
  f16x2 hL2[128];        // 512 B h (fp16)
  float red[256];
};

template <bool F32, bool I64>
__device__ void ins_rec_impl(const int* ilen32, const int* bnd32,
                             const float* __restrict__ gx,
                             const uint4* __restrict__ pk,
                             const void* wlin, const void* blin,
                             float* __restrict__ out, int B, InsSmem& sm) {
  const int b = blockIdx.x, t = threadIdx.x;
  const int j = t >> 8, rr = t & 255;
  const int len = ldi<I64>(ilen32, b);
  const long n0 = (long)ldi<I64>(bnd32, b);
#pragma unroll
  for (int cc = 0; cc < LCH; ++cc)
    sm.wL[cc][t] = pk[((RCH + cc) * 4 + j) * 256 + rr];
  uint4 wr[RCH];
#pragma unroll
  for (int cg = 0; cg < RCH; ++cg)
    wr[cg] = pk[(cg * 4 + j) * 256 + rr];
  if (t < 128) {
    f16x2 z; z.x = (_Float16)0.f; z.y = (_Float16)0.f;
    sm.hL2[t] = z;
  }
  float c = 0.f, h = 0.f;
  // gx prefetch pipeline: g holds step m's gates; loads for m+1 issue at the
  // top of step m, vmcnt-wait lands a full iteration later (dots+2 barriers
  // +activation ~2us of work) -> HBM/L2 latency off the serial critical path.
  float g0 = 0.f, g1 = 0.f, g2 = 0.f, g3 = 0.f;
  if (t < 256 && len > 0) {
    const float* gp = gx + (size_t)n0 * G4;
    g0 = gp[t]; g1 = gp[256 + t]; g2 = gp[512 + t]; g3 = gp[768 + t];
  }
  __syncthreads();

  for (int m = 0; m < len; ++m) {
    float p0 = 0.f, p1 = 0.f, p2 = 0.f, p3 = 0.f;
    if (t < 256 && m + 1 < len) {
      const float* gp = gx + (size_t)(n0 + m + 1) * G4;
      p0 = gp[t]; p1 = gp[256 + t]; p2 = gp[512 + t]; p3 = gp[768 + t];
    }
    float a0 = 0.f, a1 = 0.f;
#pragma unroll
    for (int cg = 0; cg < RCH; ++cg) {
      float4 hv = ((const float4*)sm.hL2)[cg];
      if (cg & 1) a1 = dot8h(wr[cg], hv, a1);
      else        a0 = dot8h(wr[cg], hv, a0);
    }
#pragma unroll
    for (int cc = 0; cc < LCH; ++cc) {
      float4 hv = ((const float4*)sm.hL2)[RCH + cc];
      if (cc & 1) a1 = dot8h(sm.wL[cc][t], hv, a1);
      else        a0 = dot8h(sm.wL[cc][t], hv, a0);
    }
    sm.gL[t] = a0 + a1;
    __syncthreads();
    if (t < 256) {
      float gi = g0 + sm.gL[t];
      float gf = g1 + sm.gL[256 + t];
      float gg = g2 + sm.gL[512 + t];
      float go = g3 + sm.gL[768 + t];
      float si = sigm(gi), sf = sigm(gf), tg = tanh_fast(gg), so = sigm(go);
      c = sf * c + si * tg;
      h = so * tanh_fast(c);
      ((_Float16*)sm.hL2)[t] = (_Float16)h;
    }
    __syncthreads();
    g0 = p0; g1 = p1; g2 = p2; g3 = p3;
  }
  if (t < 256) sm.red[t] = h * ldf<F32>(wlin, t);
  __syncthreads();
  for (int st = 128; st > 0; st >>= 1) {
    if (t < st) sm.red[t] += sm.red[t + st];
    __syncthreads();
  }
  if (t == 0) out[b] = sm.red[0] + ldf<F32>(blin, 0);
}

__global__ __launch_bounds__(1024) void k_ins_rec(
    const int* ilen32, const int* bnd32, const float* __restrict__ gx,
    const uint4* __restrict__ pk, const void* wlin, const void* blin,
    float* __restrict__ out, int B, const void* fprobe, const int* iprobe) {
  __shared__ InsSmem sm;
  __shared__ int sfl;
  if (threadIdx.x == 0)
    sfl = (is_f32(fprobe) ? 1 : 0) | ((iprobe[1] == 0) ? 2 : 0);
  __syncthreads();
  const int fl = sfl;
  if (fl == 0)      ins_rec_impl<false, false>(ilen32, bnd32, gx, pk, wlin, blin, out, B, sm);
  else if (fl == 1) ins_rec_impl<true,  false>(ilen32, bnd32, gx, pk, wlin, blin, out, B, sm);
  else if (fl == 2) ins_rec_impl<false, true >(ilen32, bnd32, gx, pk, wlin, blin, out, B, sm);
  else              ins_rec_impl<true,  true >(ilen32, bnd32, gx, pk, wlin, blin, out, B, sm);
}

// ===== fallback (no gx workspace): fp32, 4 blocks per WG =====
#define IBB 4
struct InsSmemFB {
  float hL[IBB][HDIM];
  float xL[IBB][HDIM];
  float gL[IBB][G4];
};

template <bool F32, bool I64>
__device__ void ins_fb_impl(const int* ilen32, const int* bnd32,
                            const float* __restrict__ instrH,
                            const float* __restrict__ wTih,
                            const float* __restrict__ wThh,
                            const void* bih, const void* bhh,
                            const void* wlin, const void* blin,
                            float* __restrict__ out, int B, InsSmemFB& sm) {
  const int wg = blockIdx.x, t = threadIdx.x;
  const int myblk = t >> 8, myelem = t & 255;
  int len[IBB], n0[IBB];
#pragma unroll
  for (int i = 0; i < IBB; ++i) {
    int b = wg * IBB + i;
    len[i] = (b < B) ? ldi<I64>(ilen32, b) : 0;
    n0[i]  = (b < B) ? ldi<I64>(bnd32, b) : 0;
  }
  float c = 0.f;
  sm.hL[myblk][myelem] = 0.f;
  float bias_r = ldf<F32>(bih, t) + ldf<F32>(bhh, t);
  __syncthreads();
  int maxlen = 0;
#pragma unroll
  for (int i = 0; i < IBB; ++i) maxlen = max(maxlen, len[i]);
  for (int m = 0; m < maxlen; ++m) {
    unsigned act = 0;
#pragma unroll
    for (int i = 0; i < IBB; ++i) if (m < len[i]) act |= (1u << i);
    if (m < len[myblk])
      sm.xL[myblk][myelem] = instrH[(size_t)(n0[myblk] + m) * HDIM + myelem];
    __syncthreads();
    float a[IBB];
#pragma unroll
    for (int i = 0; i < IBB; ++i) a[i] = (act & (1u << i)) ? bias_r : 0.f;
    for (int k4 = 0; k4 < 64; ++k4) {
      float w0 = wThh[(size_t)(k4 * 4 + 0) * 1024 + t];
      float w1 = wThh[(size_t)(k4 * 4 + 1) * 1024 + t];
      float w2 = wThh[(size_t)(k4 * 4 + 2) * 1024 + t];
      float w3 = wThh[(size_t)(k4 * 4 + 3) * 1024 + t];
      float u0 = wTih[(size_t)(k4 * 4 + 0) * 1024 + t];
      float u1 = wTih[(size_t)(k4 * 4 + 1) * 1024 + t];
      float u2 = wTih[(size_t)(k4 * 4 + 2) * 1024 + t];
      float u3 = wTih[(size_t)(k4 * 4 + 3) * 1024 + t];
#pragma unroll
      for (int i = 0; i < IBB; ++i) {
        if (!(act & (1u << i))) continue;
        float4 h4 = *(const float4*)&sm.hL[i][k4 * 4];
        float4 x4 = *(const float4*)&sm.xL[i][k4 * 4];
        a[i] = fmaf(h4.x, w0, fmaf(h4.y, w1, fmaf(h4.z, w2, fmaf(h4.w, w3, a[i]))));
        a[i] = fmaf(x4.x, u0, fmaf(x4.y, u1, fmaf(x4.z, u2, fmaf(x4.w, u3, a[i]))));
      }
    }
#pragma unroll
    for (int i = 0; i < IBB; ++i)
      if (act & (1u << i)) sm.gL[i][t] = a[i];
    __syncthreads();
    if (m < len[myblk]) {
      float si = sigm(sm.gL[myblk][myelem]);
      float sf = sigm(sm.gL[myblk][256 + myelem]);
      float tg = tanh_fast(sm.gL[myblk][512 + myelem]);
      float so = sigm(sm.gL[myblk][768 + myelem]);
      c = sf * c + si * tg;
      sm.hL[myblk][myelem] = so * tanh_fast(c);
    }
    __syncthreads();
  }
  sm.gL[myblk][myelem] = sm.hL[myblk][myelem] * ldf<F32>(wlin, myelem);
  __syncthreads();
  for (int st = 128; st > 0; st >>= 1) {
    if (myelem < st) sm.gL[myblk][myelem] += sm.gL[myblk][myelem + st];
    __syncthreads();
  }
  if (myelem == 0 && wg * IBB + myblk < B)
    out[wg * IBB + myblk] = sm.gL[myblk][0] + ldf<F32>(blin, 0);
}

__global__ __launch_bounds__(1024) void k_ins_fb(
    const int* ilen32, const int* bnd32, const float* __restrict__ instrH,
    const float* __restrict__ wTih, const float* __restrict__ wThh,
    const void* bih, const void* bhh, const void* wlin, const void* blin,
    float* __restrict__ out, int B, const void* fprobe, const int* iprobe) {
  __shared__ InsSmemFB sm;
  __shared__ int sfl;
  if (threadIdx.x == 0)
    sfl = (is_f32(fprobe) ? 1 : 0) | ((iprobe[1] == 0) ? 2 : 0);
  __syncthreads();
  const int fl = sfl;
  if (fl == 0)      ins_fb_impl<false, false>(ilen32, bnd32, instrH, wTih, wThh, bih, bhh, wlin, blin, out, B, sm);
  else if (fl == 1) ins_fb_impl<true,  false>(ilen32, bnd32, instrH, wTih, wThh, bih, bhh, wlin, blin, out, B, sm);
  else if (fl == 2) ins_fb_impl<false, true >(ilen32, bnd32, instrH, wTih, wThh, bih, bhh, wlin, blin, out, B, sm);
  else              ins_fb_impl<true,  true >(ilen32, bnd32, instrH, wTih, wThh, bih, bhh, wlin, blin, out, B, sm);
}

extern "C" void kernel_launch(void* const* d_in, const int* in_sizes, int n_in,
                              void* d_out, int out_size, void* d_ws, size_t ws_size,
                              hipStream_t stream) {
  const int N = in_sizes[1];   // total instructions
  const int B = in_sizes[2];   // basic blocks

  // ---- workspace layout (float units) ----
  float* ws = (float*)d_ws;
  size_t off = 0;
  f16x4* tabi4 = (f16x4*)(ws + off); off += (size_t)VSZ * G4 / 2;  // 4 MB fp16
  float* instrH   = ws + off; off += (size_t)N * HDIM;
  float* wT_ihI   = ws + off; off += 262144;               // w_ih_ins^T fp32 (fb)
  float* wT_hhI   = ws + off; off += 262144;               // w_hh_ins^T fp32 (fb)
  float* wT_ihT   = ws + off; off += 262144;               // w_ih_tok^T fp32
  f16x8* pkB_tok  = (f16x8*)(ws + off); off += 131072;     // MFMA B-frag w_hh_tok
  f16x8* pkB_ins  = (f16x8*)(ws + off); off += 131072;     // MFMA B-frag w_ih_ins (fused gx)
  uint4* pk_ins   = (uint4*)(ws + off); off += 131072;     // row-gang fp16 w_hh_ins
  int*   permI    = (int*)(ws + off);
  off += ((size_t)N + 15) & ~(size_t)15;
  float* gx       = ws + off;
  const size_t need_gx = (off + (size_t)N * G4) * sizeof(float);
  const bool has_gx = (ws_size >= need_gx);

  const void* fprobe = d_in[5];              // w_ih_tok
  const int*  iprobe = (const int*)d_in[1];  // token_lengths

  hipLaunchKernelGGL(k_transp, dim3(32, 8), dim3(256), 0, stream, d_in[5], wT_ihT, fprobe);
  hipLaunchKernelGGL(k_transp, dim3(32, 8), dim3(256), 0, stream, d_in[9], wT_ihI, fprobe);
  hipLaunchKernelGGL(k_transp, dim3(32, 8), dim3(256), 0, stream, d_in[10], wT_hhI, fprobe);
  hipLaunchKernelGGL(k_packB, dim3(128), dim3(256), 0, stream, d_in[6], pkB_tok, fprobe);
  hipLaunchKernelGGL(k_packB, dim3(128), dim3(256), 0, stream, d_in[9], pkB_ins, fprobe);
  hipLaunchKernelGGL(k_pack, dim3(128), dim3(256), 0, stream, d_in[10], pk_ins, fprobe);

  hipLaunchKernelGGL(k_tok_table, dim3(VSZ / 16), dim3(256), 0, stream,
                     d_in[4], wT_ihT, d_in[7], d_in[8], tabi4, fprobe);
  hipLaunchKernelGGL(k_bucket, dim3(1), dim3(1024), 0, stream,
                     (const int*)d_in[1], N, permI, iprobe);
  hipLaunchKernelGGL(k_tok_lstm, dim3((N + IB - 1) / IB), dim3(256), 0, stream,
                     (const int*)d_in[0], (const int*)d_in[1], permI, tabi4,
                     pkB_tok, pkB_ins, d_in[11], d_in[12], instrH, gx, N,
                     has_gx ? 1 : 0, iprobe, fprobe);
  if (has_gx) {
    hipLaunchKernelGGL(k_ins_rec, dim3(B), dim3(1024), 0, stream,
                       (const int*)d_in[2], (const int*)d_in[3], gx, pk_ins,
                       d_in[13], d_in[14], (float*)d_out, B, fprobe, iprobe);
  } else {
    hipLaunchKernelGGL(k_ins_fb, dim3((B + IBB - 1) / IBB), dim3(1024), 0, stream,
                       (const int*)d_in[2], (const int*)d_in[3], instrH,
                       wT_ihI, wT_hhI, d_in[11], d_in[12], d_in[13], d_in[14],
                       (float*)d_out, B, fprobe, iprobe);
  }
}

// Round 12
// 641.355 us; speedup vs baseline: 2.2593x; 1.0866x over previous
//
#include <hip/hip_runtime.h>
#include <hip/hip_bf16.h>
#include <math.h>

#define VSZ 2048
#define EDIM 256
#define HDIM 256
#define G4 1024   // 4*H
#define TMAX 16
#define IB 16     // instructions per workgroup in token-LSTM (MFMA M=16)

typedef _Float16 f16x2 __attribute__((ext_vector_type(2)));
typedef _Float16 f16x4 __attribute__((ext_vector_type(4)));
typedef _Float16 f16x8 __attribute__((ext_vector_type(8)));
typedef float f32x4 __attribute__((ext_vector_type(4)));

#define HA_STRIDE 264    // fp16 elems per hA row (256 + 8 pad)
#define GWH_STRIDE 264   // fp16 elems per gate-staging row (256 + 8 pad)

// ---- fast activations: v_exp_f32 / v_rcp_f32 based (verified rounds 2-11) ----
__device__ __forceinline__ float fexp2(float x) {
#if defined(__has_builtin) && __has_builtin(__builtin_amdgcn_exp2f)
  return __builtin_amdgcn_exp2f(x);
#else
  return exp2f(x);
#endif
}
__device__ __forceinline__ float frcp(float x) {
#if defined(__has_builtin) && __has_builtin(__builtin_amdgcn_rcpf)
  return __builtin_amdgcn_rcpf(x);
#else
  return 1.0f / x;
#endif
}
__device__ __forceinline__ float sigm(float x) {
  return frcp(1.0f + fexp2(x * -1.44269504f));
}
__device__ __forceinline__ float tanh_fast(float x) {
  float t = fexp2(fminf(x, 15.0f) * 2.88539008f);
  return (t - 1.0f) * frcp(t + 1.0f);
}

__device__ __forceinline__ float fdot2(f16x2 a, f16x2 b, float c) {
#if defined(__has_builtin) && __has_builtin(__builtin_amdgcn_fdot2)
  return __builtin_amdgcn_fdot2(a, b, c, false);
#else
  return c + (float)a.x * (float)b.x + (float)a.y * (float)b.y;
#endif
}

__device__ __forceinline__ float dot8h(uint4 w, float4 hv, float acc) {
  f16x2 h0 = __builtin_bit_cast(f16x2, hv.x);
  f16x2 h1 = __builtin_bit_cast(f16x2, hv.y);
  f16x2 h2 = __builtin_bit_cast(f16x2, hv.z);
  f16x2 h3 = __builtin_bit_cast(f16x2, hv.w);
  f16x2 w0 = __builtin_bit_cast(f16x2, w.x);
  f16x2 w1 = __builtin_bit_cast(f16x2, w.y);
  f16x2 w2 = __builtin_bit_cast(f16x2, w.z);
  f16x2 w3 = __builtin_bit_cast(f16x2, w.w);
  return fdot2(h3, w3, fdot2(h2, w2, fdot2(h1, w1, fdot2(h0, w0, acc))));
}

// ---- dtype probes ----
__device__ __forceinline__ bool is_f32(const void* w) {
  const unsigned short* p = (const unsigned short*)w;
  int pl = 0;
#pragma unroll
  for (int i = 0; i < 64; ++i) {
    unsigned e = (p[2 * i] >> 7) & 0xFF;
    pl += (e >= 113 && e <= 122) ? 1 : 0;
  }
  return pl < 48;
}

// ---- typed loads ----
template <bool F32>
__device__ __forceinline__ float ldf(const void* p, long j) {
  if (F32) return ((const float*)p)[j];
  return __uint_as_float(((unsigned)((const unsigned short*)p)[j]) << 16);
}
__device__ __forceinline__ float ldf_rt(const void* p, long j, bool f32) {
  if (f32) return ((const float*)p)[j];
  return __uint_as_float(((unsigned)((const unsigned short*)p)[j]) << 16);
}
template <bool I64>
__device__ __forceinline__ int ldi(const int* p, int j) {
  return I64 ? p[2 * j] : p[j];
}
__device__ __forceinline__ int ldi_rt(const int* p, int j, bool i64) {
  return i64 ? p[2 * j] : p[j];
}

// ===== fp32 transpose: dst[k*1024 + r] = src[r*256 + k] (fallback path only) =====
__global__ __launch_bounds__(256) void k_transp(const void* src, float* __restrict__ dst,
                                                const void* fprobe) {
  __shared__ float tile[32][33];
  __shared__ int sf;
  if (threadIdx.x == 0) sf = is_f32(fprobe) ? 1 : 0;
  __syncthreads();
  const bool f32 = (sf != 0);
  const int tx = threadIdx.x & 31, ty = threadIdx.x >> 5;
  const int r0 = blockIdx.x * 32, c0 = blockIdx.y * 32;
#pragma unroll
  for (int q = 0; q < 4; ++q) {
    int rr = ty + q * 8;
    tile[rr][tx] = ldf_rt(src, (long)(r0 + rr) * 256 + (c0 + tx), f32);
  }
  __syncthreads();
#pragma unroll
  for (int q = 0; q < 4; ++q) {
    int cc = ty + q * 8;
    dst[(size_t)(c0 + cc) * 1024 + (r0 + tx)] = tile[tx][cc];
  }
}

// ===== fp16 weight packing (row-gang layout for k_ins_rec) =====
__global__ __launch_bounds__(256) void k_pack(const void* src, uint4* __restrict__ dst,
                                              const void* fprobe) {
  __shared__ int sf;
  if (threadIdx.x == 0) sf = is_f32(fprobe) ? 1 : 0;
  __syncthreads();
  const bool f32 = (sf != 0);
  const int idx = blockIdx.x * 256 + threadIdx.x;  // grid 128
  const int rr = idx & 255, j = (idx >> 8) & 3, c = idx >> 10;
  const long base = (long)(j * 256 + rr) * 256 + 8 * c;
  unsigned u[4];
#pragma unroll
  for (int q = 0; q < 4; ++q) {
    f16x2 v;
    v.x = (_Float16)ldf_rt(src, base + 2 * q, f32);
    v.y = (_Float16)ldf_rt(src, base + 2 * q + 1, f32);
    u[q] = __builtin_bit_cast(unsigned, v);
  }
  uint4 o; o.x = u[0]; o.y = u[1]; o.z = u[2]; o.w = u[3];
  dst[idx] = o;
}

// ===== MFMA B-fragment packing (gate col n = e*4 + j) =====
__global__ __launch_bounds__(256) void k_packB(const void* src, f16x8* __restrict__ dst,
                                               const void* fprobe) {
  __shared__ int sf;
  if (threadIdx.x == 0) sf = is_f32(fprobe) ? 1 : 0;
  __syncthreads();
  const bool f32 = (sf != 0);
  const int idx = blockIdx.x * 256 + threadIdx.x;  // 0..32767, grid 128
  const int l = idx & 63;
  int rest = idx >> 6;
  const int kt = rest & 7; rest >>= 3;
  const int nt = rest & 15;
  const int w = rest >> 4;
  const int n = 256 * w + nt * 16 + (l & 15);
  const int j = n & 3, e = n >> 2;
  const long base = (long)(j * 256 + e) * 256 + kt * 32 + ((l >> 4) << 3);
  f16x8 v;
#pragma unroll
  for (int q = 0; q < 8; ++q) v[q] = (_Float16)ldf_rt(src, base + q, f32);
  dst[idx] = v;
}

// ===== kernel 1: token gate table via MFMA (replaces fp32 VALU GEMM) =====
// Same verified structure as the tok_lstm gx phase: A = 16 emb rows (hA
// layout), B = packed w_ih_tok, epilogue gv[4l..4l+3] = (i,f,g,o) of elem t.
struct TTSmem {
  _Float16 gateW[4][16 * GWH_STRIDE];  // 33792 B
  _Float16 hA[16 * HA_STRIDE];         // 8448 B
};

__global__ __launch_bounds__(256, 2) void k_tok_tableM(
    const void* emb, const f16x8* __restrict__ pkBT, const void* bih,
    const void* bhh, f16x4* __restrict__ tabi4, const void* fprobe) {
  __shared__ TTSmem sm;
  __shared__ int sf;
  if (threadIdx.x == 0) sf = is_f32(fprobe) ? 1 : 0;
  __syncthreads();
  const bool f32 = (sf != 0);
  const int t = threadIdx.x, w = t >> 6, l = t & 63;
  const int v0 = blockIdx.x * 16;
#pragma unroll
  for (int i = 0; i < 16; ++i)
    sm.hA[i * HA_STRIDE + t] = (_Float16)ldf_rt(emb, (long)(v0 + i) * EDIM + t, f32);
  __syncthreads();

  const int aOff = (l & 15) * HA_STRIDE + ((l >> 4) << 3);
  const int m0 = (l >> 4) << 2;
  _Float16* gw = sm.gateW[w];
  f16x8 aF[8];
#pragma unroll
  for (int kt = 0; kt < 8; ++kt)
    aF[kt] = *(const f16x8*)&sm.hA[aOff + kt * 32];
  const f16x8* Bp = pkBT + (size_t)w * (16 * 8 * 64);
#pragma unroll 2
  for (int g4 = 0; g4 < 4; ++g4) {
    f32x4 a0 = {0.f, 0.f, 0.f, 0.f}, a1 = a0, a2 = a0, a3 = a0;
#pragma unroll
    for (int kt = 0; kt < 8; ++kt) {
      const f16x8* bb = Bp + ((size_t)(g4 * 4) * 8 + kt) * 64 + l;
      f16x8 b0 = bb[0 * 8 * 64];
      f16x8 b1 = bb[1 * 8 * 64];
      f16x8 b2 = bb[2 * 8 * 64];
      f16x8 b3 = bb[3 * 8 * 64];
      a0 = __builtin_amdgcn_mfma_f32_16x16x32_f16(aF[kt], b0, a0, 0, 0, 0);
      a1 = __builtin_amdgcn_mfma_f32_16x16x32_f16(aF[kt], b1, a1, 0, 0, 0);
      a2 = __builtin_amdgcn_mfma_f32_16x16x32_f16(aF[kt], b2, a2, 0, 0, 0);
      a3 = __builtin_amdgcn_mfma_f32_16x16x32_f16(aF[kt], b3, a3, 0, 0, 0);
    }
    const int colb = (l & 15);
#pragma unroll
    for (int r = 0; r < 4; ++r) {
      gw[(m0 + r) * GWH_STRIDE + (g4 * 4 + 0) * 16 + colb] = (_Float16)a0[r];
      gw[(m0 + r) * GWH_STRIDE + (g4 * 4 + 1) * 16 + colb] = (_Float16)a1[r];
      gw[(m0 + r) * GWH_STRIDE + (g4 * 4 + 2) * 16 + colb] = (_Float16)a2[r];
      gw[(m0 + r) * GWH_STRIDE + (g4 * 4 + 3) * 16 + colb] = (_Float16)a3[r];
    }
  }
  __syncthreads();
  const float bj0 = ldf_rt(bih, 0 * 256 + t, f32) + ldf_rt(bhh, 0 * 256 + t, f32);
  const float bj1 = ldf_rt(bih, 1 * 256 + t, f32) + ldf_rt(bhh, 1 * 256 + t, f32);
  const float bj2 = ldf_rt(bih, 2 * 256 + t, f32) + ldf_rt(bhh, 2 * 256 + t, f32);
  const float bj3 = ldf_rt(bih, 3 * 256 + t, f32) + ldf_rt(bhh, 3 * 256 + t, f32);
#pragma unroll
  for (int m = 0; m < 16; ++m) {
    f16x4 gv = *(const f16x4*)&gw[m * GWH_STRIDE + 4 * l];
    f16x4 v;
    v.x = (_Float16)((float)gv.x + bj0);
    v.y = (_Float16)((float)gv.y + bj1);
    v.z = (_Float16)((float)gv.z + bj2);
    v.w = (_Float16)((float)gv.w + bj3);
    tabi4[(size_t)(v0 + m) * 256 + t] = v;
  }
}

// ===== length bucketing: single WG, per-wave histograms =====
__global__ __launch_bounds__(1024) void k_bucket(const int* tlen, int N,
                                                 int* __restrict__ perm,
                                                 const int* iprobe) {
  __shared__ int cnt[16][18];    // per-wave counts / cursors
  __shared__ int wbase[16][18];  // per-wave start within bucket
  __shared__ int base[18];
  const int t = threadIdx.x;
  const int w = t >> 6;
  const bool i64 = (iprobe[1] == 0);
  if (t < 16 * 18) ((int*)cnt)[t] = 0;
  __syncthreads();
  for (int n = t; n < N; n += 1024) {
    int len = ldi_rt(tlen, n, i64);
    len = max(0, min(16, len));
    atomicAdd(&cnt[w][len], 1);
  }
  __syncthreads();
  if (t < 17) {
    int s = 0;
    for (int ww = 0; ww < 16; ++ww) { wbase[ww][t] = s; s += cnt[ww][t]; }
    base[t] = s;   // bucket totals (pre-scan)
  }
  __syncthreads();
  if (t == 0) {
    int s = 0;
    for (int i = 0; i <= 16; ++i) { int c = base[i]; base[i] = s; s += c; }
  }
  __syncthreads();
  if (t < 16 * 18) ((int*)cnt)[t] = 0;   // reuse as per-wave cursors
  __syncthreads();
  for (int n = t; n < N; n += 1024) {
    int len = ldi_rt(tlen, n, i64);
    len = max(0, min(16, len));
    int pos = base[len] + wbase[w][len] + atomicAdd(&cnt[w][len], 1);
    perm[pos] = n;
  }
}

// ===== kernel 2: token LSTM — round-8 shape EXACT (354us, VGPR 76 proven) =====
struct TokSmemM {
  _Float16 gateW[4][16 * GWH_STRIDE];  // 33792 B: per-wave D staging (fp16)
  _Float16 hA[16 * HA_STRIDE];         // 8448 B: h in MFMA-A layout (fp16)
  int tokL[IB][TMAX];
  int lenL[IB];
  int nIdx[IB];
};

template <bool I64>
__device__ void tok_mfma_impl(const int* tok32, const int* tlen32,
                              const int* __restrict__ perm,
                              const f16x4* __restrict__ tabi4,
                              const f16x8* __restrict__ pkB,
                              const f16x8* __restrict__ pkBI,
                              const void* bihI, const void* bhhI,
                              float* __restrict__ instrH, float* __restrict__ gx,
                              int N, int do_gx, bool f32, TokSmemM& sm) {
  const int n0 = blockIdx.x * IB, t = threadIdx.x;
  const int w = t >> 6, l = t & 63;
  if (t < IB) {
    int slot = n0 + t;
    int n = (slot < N) ? perm[slot] : -1;
    sm.nIdx[t] = n;
    sm.lenL[t] = (n >= 0) ? ldi<I64>(tlen32, n) : 0;
  }
  for (int idx = t; idx < 16 * HA_STRIDE / 2; idx += 256) ((unsigned*)sm.hA)[idx] = 0;
  __syncthreads();
  {
    int i = t >> 4, s = t & 15;
    int n = sm.nIdx[i];
    sm.tokL[i][s] = (n >= 0) ? ldi<I64>(tok32, n * TMAX + s) : 0;
  }
  float c[IB];
#pragma unroll
  for (int i = 0; i < IB; ++i) c[i] = 0.f;
  __syncthreads();
  int maxlen = 0;
#pragma unroll
  for (int i = 0; i < IB; ++i) maxlen = max(maxlen, sm.lenL[i]);

  const f16x8* Bp = pkB + (size_t)w * (16 * 8 * 64);
  const int aOff = (l & 15) * HA_STRIDE + ((l >> 4) << 3);
  const int m0 = (l >> 4) << 2;
  _Float16* gw = sm.gateW[w];

  for (int s = 0; s < maxlen; ++s) {
    f16x8 aF[8];
#pragma unroll
    for (int kt = 0; kt < 8; ++kt)
      aF[kt] = *(const f16x8*)&sm.hA[aOff + kt * 32];
    // unroll 2: overlap two MFMA chains without spilling (96 VGPR proven)
#pragma unroll 2
    for (int g4 = 0; g4 < 4; ++g4) {
      f32x4 a0 = {0.f, 0.f, 0.f, 0.f}, a1 = a0, a2 = a0, a3 = a0;
#pragma unroll
      for (int kt = 0; kt < 8; ++kt) {
        const f16x8* bb = Bp + ((size_t)(g4 * 4) * 8 + kt) * 64 + l;
        f16x8 b0 = bb[0 * 8 * 64];
        f16x8 b1 = bb[1 * 8 * 64];
        f16x8 b2 = bb[2 * 8 * 64];
        f16x8 b3 = bb[3 * 8 * 64];
        a0 = __builtin_amdgcn_mfma_f32_16x16x32_f16(aF[kt], b0, a0, 0, 0, 0);
        a1 = __builtin_amdgcn_mfma_f32_16x16x32_f16(aF[kt], b1, a1, 0, 0, 0);
        a2 = __builtin_amdgcn_mfma_f32_16x16x32_f16(aF[kt], b2, a2, 0, 0, 0);
        a3 = __builtin_amdgcn_mfma_f32_16x16x32_f16(aF[kt], b3, a3, 0, 0, 0);
      }
      const int colb = (l & 15);
#pragma unroll
      for (int r = 0; r < 4; ++r) {
        gw[(m0 + r) * GWH_STRIDE + (g4 * 4 + 0) * 16 + colb] = (_Float16)a0[r];
        gw[(m0 + r) * GWH_STRIDE + (g4 * 4 + 1) * 16 + colb] = (_Float16)a1[r];
        gw[(m0 + r) * GWH_STRIDE + (g4 * 4 + 2) * 16 + colb] = (_Float16)a2[r];
        gw[(m0 + r) * GWH_STRIDE + (g4 * 4 + 3) * 16 + colb] = (_Float16)a3[r];
      }
    }
    __syncthreads();
    // epilogue: FULL unroll, fp16 gate slice read (8B, 2-way bank = free)
#pragma unroll
    for (int m = 0; m < IB; ++m) {
      if (s < sm.lenL[m]) {
        f16x4 gv = *(const f16x4*)&gw[m * GWH_STRIDE + 4 * l];
        f16x4 tb = tabi4[(size_t)sm.tokL[m][s] * 256 + t];
        float gi = (float)gv.x + (float)tb.x;
        float gf = (float)gv.y + (float)tb.y;
        float gg = (float)gv.z + (float)tb.z;
        float go = (float)gv.w + (float)tb.w;
        float si = sigm(gi), sf = sigm(gf), tg = tanh_fast(gg), so = sigm(go);
        c[m] = sf * c[m] + si * tg;
        sm.hA[m * HA_STRIDE + t] = (_Float16)(so * tanh_fast(c[m]));
      }
    }
    __syncthreads();
  }
#pragma unroll
  for (int m = 0; m < IB; ++m) {
    int n = sm.nIdx[m];
    if (n >= 0) instrH[(size_t)n * HDIM + t] = (float)sm.hA[m * HA_STRIDE + t];
  }
  // ===== fused gx phase: gx = hA @ w_ih_ins^T + biases (fp16 staging) =====
  if (do_gx) {
    f16x8 aF[8];
#pragma unroll
    for (int kt = 0; kt < 8; ++kt)
      aF[kt] = *(const f16x8*)&sm.hA[aOff + kt * 32];
    const f16x8* BpI = pkBI + (size_t)w * (16 * 8 * 64);
#pragma unroll 2
    for (int g4 = 0; g4 < 4; ++g4) {
      f32x4 a0 = {0.f, 0.f, 0.f, 0.f}, a1 = a0, a2 = a0, a3 = a0;
#pragma unroll
      for (int kt = 0; kt < 8; ++kt) {
        const f16x8* bb = BpI + ((size_t)(g4 * 4) * 8 + kt) * 64 + l;
        f16x8 b0 = bb[0 * 8 * 64];
        f16x8 b1 = bb[1 * 8 * 64];
        f16x8 b2 = bb[2 * 8 * 64];
        f16x8 b3 = bb[3 * 8 * 64];
        a0 = __builtin_amdgcn_mfma_f32_16x16x32_f16(aF[kt], b0, a0, 0, 0, 0);
        a1 = __builtin_amdgcn_mfma_f32_16x16x32_f16(aF[kt], b1, a1, 0, 0, 0);
        a2 = __builtin_amdgcn_mfma_f32_16x16x32_f16(aF[kt], b2, a2, 0, 0, 0);
        a3 = __builtin_amdgcn_mfma_f32_16x16x32_f16(aF[kt], b3, a3, 0, 0, 0);
      }
      const int colb = (l & 15);
#pragma unroll
      for (int r = 0; r < 4; ++r) {
        gw[(m0 + r) * GWH_STRIDE + (g4 * 4 + 0) * 16 + colb] = (_Float16)a0[r];
        gw[(m0 + r) * GWH_STRIDE + (g4 * 4 + 1) * 16 + colb] = (_Float16)a1[r];
        gw[(m0 + r) * GWH_STRIDE + (g4 * 4 + 2) * 16 + colb] = (_Float16)a2[r];
        gw[(m0 + r) * GWH_STRIDE + (g4 * 4 + 3) * 16 + colb] = (_Float16)a3[r];
      }
    }
    __syncthreads();
    const float bj0 = ldf_rt(bihI, 0 * 256 + t, f32) + ldf_rt(bhhI, 0 * 256 + t, f32);
    const float bj1 = ldf_rt(bihI, 1 * 256 + t, f32) + ldf_rt(bhhI, 1 * 256 + t, f32);
    const float bj2 = ldf_rt(bihI, 2 * 256 + t, f32) + ldf_rt(bhhI, 2 * 256 + t, f32);
    const float bj3 = ldf_rt(bihI, 3 * 256 + t, f32) + ldf_rt(bhhI, 3 * 256 + t, f32);
#pragma unroll
    for (int m = 0; m < IB; ++m) {
      int n = sm.nIdx[m];
      if (n >= 0) {
        f16x4 gv = *(const f16x4*)&gw[m * GWH_STRIDE + 4 * l];
        gx[(size_t)n * G4 +       t] = (float)gv.x + bj0;
        gx[(size_t)n * G4 + 256 + t] = (float)gv.y + bj1;
        gx[(size_t)n * G4 + 512 + t] = (float)gv.z + bj2;
        gx[(size_t)n * G4 + 768 + t] = (float)gv.w + bj3;
      }
    }
  }
}

__global__ __launch_bounds__(256, 2) void k_tok_lstm(
    const int* tok32, const int* tlen32, const int* __restrict__ perm,
    const f16x4* __restrict__ tabi4, const f16x8* __restrict__ pkB,
    const f16x8* __restrict__ pkBI, const void* bihI, const void* bhhI,
    float* __restrict__ instrH, float* __restrict__ gx, int N, int do_gx,
    const int* iprobe, const void* fprobe) {
  __shared__ TokSmemM sm;
  __shared__ int sfl;
  if (threadIdx.x == 0)
    sfl = ((iprobe[1] == 0) ? 1 : 0) | (is_f32(fprobe) ? 2 : 0);
  __syncthreads();
  const bool f32 = (sfl & 2) != 0;
  if (sfl & 1) tok_mfma_impl<true >(tok32, tlen32, perm, tabi4, pkB, pkBI, bihI, bhhI, instrH, gx, N, do_gx, f32, sm);
  else         tok_mfma_impl<false>(tok32, tlen32, perm, tabi4, pkB, pkBI, bihI, bhhI, instrH, gx, N, do_gx, f32, sm);
}

// ===== kernel 3b: instruction-LSTM — weights RESIDENT in regs+LDS (r8 form) =====
#define RCH 24   // chunks in registers
#define LCH 8    // chunks in LDS
struct InsSmem {
  uint4 wL[LCH][1024];   // 128 KB resident weights (chunks RCH..31)
  float gL[1024];        // 4 KB gates
  f16x2 hL2[128];        // 512 B h (fp16)
  float red[256];
};

template <bool F32, bool I64>
__device__ void ins_rec_impl(const int* ilen32, const int* bnd32,
                             const float* __restrict__ gx,
                             const uint4* __restrict__ pk,
                             const void* wlin, const void* blin,
                             float* __restrict__ out, int B, InsSmem& sm) {
  const int b = blockIdx.x, t = threadIdx.x;
  const int j = t >> 8, rr = t & 255;
  const int len = ldi<I64>(ilen32, b);
  const long n0 = (long)ldi<I64>(bnd32, b);
#pragma unroll
  for (int cc = 0; cc < LCH; ++cc)
    sm.wL[cc][t] = pk[((RCH + cc) * 4 + j) * 256 + rr];
  uint4 wr[RCH];
#pragma unroll
  for (int cg = 0; cg < RCH; ++cg)
    wr[cg] = pk[(cg * 4 + j) * 256 + rr];
  if (t < 128) {
    f16x2 z; z.x = (_Float16)0.f; z.y = (_Float16)0.f;
    sm.hL2[t] = z;
  }
  float c = 0.f, h = 0.f;
  __syncthreads();

  for (int m = 0; m < len; ++m) {
    float g0 = 0.f, g1 = 0.f, g2 = 0.f, g3 = 0.f;
    if (t < 256) {
      const float* gp = gx + (size_t)(n0 + m) * G4;
      g0 = gp[t]; g1 = gp[256 + t]; g2 = gp[512 + t]; g3 = gp[768 + t];
    }
    float a0 = 0.f, a1 = 0.f;
#pragma unroll
    for (int cg = 0; cg < RCH; ++cg) {
      float4 hv = ((const float4*)sm.hL2)[cg];
      if (cg & 1) a1 = dot8h(wr[cg], hv, a1);
      else        a0 = dot8h(wr[cg], hv, a0);
    }
#pragma unroll
    for (int cc = 0; cc < LCH; ++cc) {
      float4 hv = ((const float4*)sm.hL2)[RCH + cc];
      if (cc & 1) a1 = dot8h(sm.wL[cc][t], hv, a1);
      else        a0 = dot8h(sm.wL[cc][t], hv, a0);
    }
    sm.gL[t] = a0 + a1;
    __syncthreads();
    if (t < 256) {
      float gi = g0 + sm.gL[t];
      float gf = g1 + sm.gL[256 + t];
      float gg = g2 + sm.gL[512 + t];
      float go = g3 + sm.gL[768 + t];
      float si = sigm(gi), sf = sigm(gf), tg = tanh_fast(gg), so = sigm(go);
      c = sf * c + si * tg;
      h = so * tanh_fast(c);
      ((_Float16*)sm.hL2)[t] = (_Float16)h;
    }
    __syncthreads();
  }
  if (t < 256) sm.red[t] = h * ldf<F32>(wlin, t);
  __syncthreads();
  for (int st = 128; st > 0; st >>= 1) {
    if (t < st) sm.red[t] += sm.red[t + st];
    __syncthreads();
  }
  if (t == 0) out[b] = sm.red[0] + ldf<F32>(blin, 0);
}

__global__ __launch_bounds__(1024) void k_ins_rec(
    const int* ilen32, const int* bnd32, const float* __restrict__ gx,
    const uint4* __restrict__ pk, const void* wlin, const void* blin,
    float* __restrict__ out, int B, const void* fprobe, const int* iprobe) {
  __shared__ InsSmem sm;
  __shared__ int sfl;
  if (threadIdx.x == 0)
    sfl = (is_f32(fprobe) ? 1 : 0) | ((iprobe[1] == 0) ? 2 : 0);
  __syncthreads();
  const int fl = sfl;
  if (fl == 0)      ins_rec_impl<false, false>(ilen32, bnd32, gx, pk, wlin, blin, out, B, sm);
  else if (fl == 1) ins_rec_impl<true,  false>(ilen32, bnd32, gx, pk, wlin, blin, out, B, sm);
  else if (fl == 2) ins_rec_impl<false, true >(ilen32, bnd32, gx, pk, wlin, blin, out, B, sm);
  else              ins_rec_impl<true,  true >(ilen32, bnd32, gx, pk, wlin, blin, out, B, sm);
}

// ===== fallback (no gx workspace): fp32, 4 blocks per WG =====
#define IBB 4
struct InsSmemFB {
  float hL[IBB][HDIM];
  float xL[IBB][HDIM];
  float gL[IBB][G4];
};

template <bool F32, bool I64>
__device__ void ins_fb_impl(const int* ilen32, const int* bnd32,
                            const float* __restrict__ instrH,
                            const float* __restrict__ wTih,
                            const float* __restrict__ wThh,
                            const void* bih, const void* bhh,
                            const void* wlin, const void* blin,
                            float* __restrict__ out, int B, InsSmemFB& sm) {
  const int wg = blockIdx.x, t = threadIdx.x;
  const int myblk = t >> 8, myelem = t & 255;
  int len[IBB], n0[IBB];
#pragma unroll
  for (int i = 0; i < IBB; ++i) {
    int b = wg * IBB + i;
    len[i] = (b < B) ? ldi<I64>(ilen32, b) : 0;
    n0[i]  = (b < B) ? ldi<I64>(bnd32, b) : 0;
  }
  float c = 0.f;
  sm.hL[myblk][myelem] = 0.f;
  float bias_r = ldf<F32>(bih, t) + ldf<F32>(bhh, t);
  __syncthreads();
  int maxlen = 0;
#pragma unroll
  for (int i = 0; i < IBB; ++i) maxlen = max(maxlen, len[i]);
  for (int m = 0; m < maxlen; ++m) {
    unsigned act = 0;
#pragma unroll
    for (int i = 0; i < IBB; ++i) if (m < len[i]) act |= (1u << i);
    if (m < len[myblk])
      sm.xL[myblk][myelem] = instrH[(size_t)(n0[myblk] + m) * HDIM + myelem];
    __syncthreads();
    float a[IBB];
#pragma unroll
    for (int i = 0; i < IBB; ++i) a[i] = (act & (1u << i)) ? bias_r : 0.f;
    for (int k4 = 0; k4 < 64; ++k4) {
      float w0 = wThh[(size_t)(k4 * 4 + 0) * 1024 + t];
      float w1 = wThh[(size_t)(k4 * 4 + 1) * 1024 + t];
      float w2 = wThh[(size_t)(k4 * 4 + 2) * 1024 + t];
      float w3 = wThh[(size_t)(k4 * 4 + 3) * 1024 + t];
      float u0 = wTih[(size_t)(k4 * 4 + 0) * 1024 + t];
      float u1 = wTih[(size_t)(k4 * 4 + 1) * 1024 + t];
      float u2 = wTih[(size_t)(k4 * 4 + 2) * 1024 + t];
      float u3 = wTih[(size_t)(k4 * 4 + 3) * 1024 + t];
#pragma unroll
      for (int i = 0; i < IBB; ++i) {
        if (!(act & (1u << i))) continue;
        float4 h4 = *(const float4*)&sm.hL[i][k4 * 4];
        float4 x4 = *(const float4*)&sm.xL[i][k4 * 4];
        a[i] = fmaf(h4.x, w0, fmaf(h4.y, w1, fmaf(h4.z, w2, fmaf(h4.w, w3, a[i]))));
        a[i] = fmaf(x4.x, u0, fmaf(x4.y, u1, fmaf(x4.z, u2, fmaf(x4.w, u3, a[i]))));
      }
    }
#pragma unroll
    for (int i = 0; i < IBB; ++i)
      if (act & (1u << i)) sm.gL[i][t] = a[i];
    __syncthreads();
    if (m < len[myblk]) {
      float si = sigm(sm.gL[myblk][myelem]);
      float sf = sigm(sm.gL[myblk][256 + myelem]);
      float tg = tanh_fast(sm.gL[myblk][512 + myelem]);
      float so = sigm(sm.gL[myblk][768 + myelem]);
      c = sf * c + si * tg;
      sm.hL[myblk][myelem] = so * tanh_fast(c);
    }
    __syncthreads();
  }
  sm.gL[myblk][myelem] = sm.hL[myblk][myelem] * ldf<F32>(wlin, myelem);
  __syncthreads();
  for (int st = 128; st > 0; st >>= 1) {
    if (myelem < st) sm.gL[myblk][myelem] += sm.gL[myblk][myelem + st];
    __syncthreads();
  }
  if (myelem == 0 && wg * IBB + myblk < B)
    out[wg * IBB + myblk] = sm.gL[myblk][0] + ldf<F32>(blin, 0);
}

__global__ __launch_bounds__(1024) void k_ins_fb(
    const int* ilen32, const int* bnd32, const float* __restrict__ instrH,
    const float* __restrict__ wTih, const float* __restrict__ wThh,
    const void* bih, const void* bhh, const void* wlin, const void* blin,
    float* __restrict__ out, int B, const void* fprobe, const int* iprobe) {
  __shared__ InsSmemFB sm;
  __shared__ int sfl;
  if (threadIdx.x == 0)
    sfl = (is_f32(fprobe) ? 1 : 0) | ((iprobe[1] == 0) ? 2 : 0);
  __syncthreads();
  const int fl = sfl;
  if (fl == 0)      ins_fb_impl<false, false>(ilen32, bnd32, instrH, wTih, wThh, bih, bhh, wlin, blin, out, B, sm);
  else if (fl == 1) ins_fb_impl<true,  false>(ilen32, bnd32, instrH, wTih, wThh, bih, bhh, wlin, blin, out, B, sm);
  else if (fl == 2) ins_fb_impl<false, true >(ilen32, bnd32, instrH, wTih, wThh, bih, bhh, wlin, blin, out, B, sm);
  else              ins_fb_impl<true,  true >(ilen32, bnd32, instrH, wTih, wThh, bih, bhh, wlin, blin, out, B, sm);
}

extern "C" void kernel_launch(void* const* d_in, const int* in_sizes, int n_in,
                              void* d_out, int out_size, void* d_ws, size_t ws_size,
                              hipStream_t stream) {
  const int N = in_sizes[1];   // total instructions
  const int B = in_sizes[2];   // basic blocks

  // ---- workspace layout (float units) ----
  float* ws = (float*)d_ws;
  size_t off = 0;
  f16x4* tabi4 = (f16x4*)(ws + off); off += (size_t)VSZ * G4 / 2;  // 4 MB fp16
  float* instrH   = ws + off; off += (size_t)N * HDIM;
  float* wT_ihI   = ws + off; off += 262144;               // w_ih_ins^T fp32 (fb)
  float* wT_hhI   = ws + off; off += 262144;               // w_hh_ins^T fp32 (fb)
  f16x8* pkB_tIH  = (f16x8*)(ws + off); off += 131072;     // MFMA B-frag w_ih_tok (table)
  f16x8* pkB_tok  = (f16x8*)(ws + off); off += 131072;     // MFMA B-frag w_hh_tok
  f16x8* pkB_ins  = (f16x8*)(ws + off); off += 131072;     // MFMA B-frag w_ih_ins (fused gx)
  uint4* pk_ins   = (uint4*)(ws + off); off += 131072;     // row-gang fp16 w_hh_ins
  int*   permI    = (int*)(ws + off);
  off += ((size_t)N + 15) & ~(size_t)15;
  float* gx       = ws + off;
  const size_t need_gx = (off + (size_t)N * G4) * sizeof(float);
  const bool has_gx = (ws_size >= need_gx);

  const void* fprobe = d_in[5];              // w_ih_tok
  const int*  iprobe = (const int*)d_in[1];  // token_lengths

  hipLaunchKernelGGL(k_transp, dim3(32, 8), dim3(256), 0, stream, d_in[9], wT_ihI, fprobe);
  hipLaunchKernelGGL(k_transp, dim3(32, 8), dim3(256), 0, stream, d_in[10], wT_hhI, fprobe);
  hipLaunchKernelGGL(k_packB, dim3(128), dim3(256), 0, stream, d_in[5], pkB_tIH, fprobe);
  hipLaunchKernelGGL(k_packB, dim3(128), dim3(256), 0, stream, d_in[6], pkB_tok, fprobe);
  hipLaunchKernelGGL(k_packB, dim3(128), dim3(256), 0, stream, d_in[9], pkB_ins, fprobe);
  hipLaunchKernelGGL(k_pack, dim3(128), dim3(256), 0, stream, d_in[10], pk_ins, fprobe);

  hipLaunchKernelGGL(k_tok_tableM, dim3(VSZ / 16), dim3(256), 0, stream,
                     d_in[4], pkB_tIH, d_in[7], d_in[8], tabi4, fprobe);
  hipLaunchKernelGGL(k_bucket, dim3(1), dim3(1024), 0, stream,
                     (const int*)d_in[1], N, permI, iprobe);
  hipLaunchKernelGGL(k_tok_lstm, dim3((N + IB - 1) / IB), dim3(256), 0, stream,
                     (const int*)d_in[0], (const int*)d_in[1], permI, tabi4,
                     pkB_tok, pkB_ins, d_in[11], d_in[12], instrH, gx, N,
                     has_gx ? 1 : 0, iprobe, fprobe);
  if (has_gx) {
    hipLaunchKernelGGL(k_ins_rec, dim3(B), dim3(1024), 0, stream,
                       (const int*)d_in[2], (const int*)d_in[3], gx, pk_ins,
                       d_in[13], d_in[14], (float*)d_out, B, fprobe, iprobe);
  } else {
    hipLaunchKernelGGL(k_ins_fb, dim3((B + IBB - 1) / IBB), dim3(1024), 0, stream,
                       (const int*)d_in[2], (const int*)d_in[3], instrH,
                       wT_ihI, wT_hhI, d_in[11], d_in[12], d_in[13], d_in[14],
                       (float*)d_out, B, fprobe, iprobe);
  }
}